// Round 1
// baseline (409.021 us; speedup 1.0000x reference)
//
#include <hip/hip_runtime.h>
#include <cstdint>
#include <cstddef>

typedef unsigned short u16;
typedef __attribute__((ext_vector_type(8))) u16 u16x8;
typedef __attribute__((ext_vector_type(8))) __bf16 bf16x8;
typedef __attribute__((ext_vector_type(4))) float f32x4;

__device__ __forceinline__ u16 f2bf(float f) {
  unsigned u = __builtin_bit_cast(unsigned, f);
  return (u16)((u + 0x7FFFu + ((u >> 16) & 1u)) >> 16);
}
__device__ __forceinline__ float bf2f(u16 h) {
  return __builtin_bit_cast(float, (unsigned)h << 16);
}
__device__ __forceinline__ f32x4 mfma16(u16x8 a, u16x8 b, f32x4 c) {
  return __builtin_amdgcn_mfma_f32_16x16x32_bf16(
      __builtin_bit_cast(bf16x8, a), __builtin_bit_cast(bf16x8, b), c, 0, 0, 0);
}
__device__ __forceinline__ void load_lds16(const void* g, void* l) {
  __builtin_amdgcn_global_load_lds(
      (const __attribute__((address_space(1))) void*)g,
      (__attribute__((address_space(3))) void*)l, 16, 0, 0);
}

// ---------------- transpose + fp32->bf16 convert: dst[n][k] = src[k][n], zero-padded
__global__ __launch_bounds__(256) void k_trcvt(const float* __restrict__ src,
                                               u16* __restrict__ dst,
                                               int R, int C, int dR, int dC) {
  __shared__ float t[32][33];
  const int n0 = blockIdx.x * 32, k0 = blockIdx.y * 32;
  const int tx = threadIdx.x & 31, ty = threadIdx.x >> 5;
#pragma unroll
  for (int j = 0; j < 4; ++j) {
    int kk = k0 + ty + 8 * j, nn = n0 + tx;
    float v = (kk < R && nn < C) ? src[(size_t)kk * C + nn] : 0.f;
    t[ty + 8 * j][tx] = v;
  }
  __syncthreads();
#pragma unroll
  for (int j = 0; j < 4; ++j) {
    int nn = n0 + ty + 8 * j, kk = k0 + tx;
    if (nn < dC && kk < dR) dst[(size_t)nn * dR + kk] = f2bf(t[tx][ty + 8 * j]);
  }
}

// ---------------- bf16 batched transpose: dst[c][r] = src[r][c] (R,C mult of 32)
__global__ __launch_bounds__(256) void k_trbf(const u16* __restrict__ src,
                                              u16* __restrict__ dst, int R, int C) {
  __shared__ u16 t[32][33];
  const size_t base = (size_t)blockIdx.z * R * C;
  const int c0 = blockIdx.x * 32, r0 = blockIdx.y * 32;
  const int tx = threadIdx.x & 31, ty = threadIdx.x >> 5;
#pragma unroll
  for (int j = 0; j < 4; ++j)
    t[ty + 8 * j][tx] = src[base + (size_t)(r0 + ty + 8 * j) * C + c0 + tx];
  __syncthreads();
#pragma unroll
  for (int j = 0; j < 4; ++j)
    dst[base + (size_t)(c0 + ty + 8 * j) * R + r0 + tx] = t[tx][ty + 8 * j];
}

// ---------------- LayerNorm over DIM=1024, fp32 in -> bf16 out
__global__ __launch_bounds__(256) void k_lnx(const float* __restrict__ x,
                                             const float* __restrict__ g,
                                             const float* __restrict__ b,
                                             u16* __restrict__ out) {
  const int row = blockIdx.x, tid = threadIdx.x;
  float4 v = ((const float4*)(x + (size_t)row * 1024))[tid];
  float s = v.x + v.y + v.z + v.w;
  float ss = v.x * v.x + v.y * v.y + v.z * v.z + v.w * v.w;
#pragma unroll
  for (int off = 1; off < 64; off <<= 1) {
    s += __shfl_xor(s, off);
    ss += __shfl_xor(ss, off);
  }
  __shared__ float red[8];
  const int wid = tid >> 6, lane = tid & 63;
  if (lane == 0) { red[wid] = s; red[4 + wid] = ss; }
  __syncthreads();
  s = red[0] + red[1] + red[2] + red[3];
  ss = red[4] + red[5] + red[6] + red[7];
  const float mean = s * (1.f / 1024.f);
  const float var = ss * (1.f / 1024.f) - mean * mean;
  const float rstd = rsqrtf(var + 1e-5f);
  float4 gv = ((const float4*)g)[tid];
  float4 bv = ((const float4*)b)[tid];
  unsigned o0 = f2bf((v.x - mean) * rstd * gv.x + bv.x);
  unsigned o1 = f2bf((v.y - mean) * rstd * gv.y + bv.y);
  unsigned o2 = f2bf((v.z - mean) * rstd * gv.z + bv.z);
  unsigned o3 = f2bf((v.w - mean) * rstd * gv.w + bv.w);
  uint2 pk;
  pk.x = o0 | (o1 << 16);
  pk.y = o2 | (o3 << 16);
  ((uint2*)(out + (size_t)row * 1024))[tid] = pk;
}

// ---------------- bf16 GEMM: C[M][N] = A[M][K] * Bt[N][K]^T, m97-style
// MODE 0: out bf16 = acc + bias[col] (bias may be null / guarded by biasN)
// MODE 1: out fp32 = resid[row*1024+col] + (acc + bias[col]) * lsg[col]
template <int MODE>
__global__ __launch_bounds__(256) void k_gemm(const u16* __restrict__ A,
                                              const u16* __restrict__ B, int K,
                                              void* __restrict__ Cout, int ldc,
                                              const float* __restrict__ bias, int biasN,
                                              const float* __restrict__ resid,
                                              const float* __restrict__ lsg) {
  __shared__ __align__(16) u16 Alds[128 * 32];
  __shared__ __align__(16) u16 Blds[128 * 32];
  const int tid = threadIdx.x;
  const int lane = tid & 63, wave = tid >> 6;
  const int l15 = lane & 15, quad = lane >> 4;
  const int wrow = (wave >> 1) * 64, wcol = (wave & 1) * 64;
  const int bm = blockIdx.y, bn = blockIdx.x;

  const u16* Ab = A + (size_t)bm * 128 * K;
  const u16* Bb = B + (size_t)bn * 128 * K;
  const int r0 = tid >> 2;
  const int ko = (tid & 3) * 8;
  u16* ldsA = Alds + tid * 8;
  u16* ldsB = Blds + tid * 8;

  f32x4 acc[4][4];
#pragma unroll
  for (int i = 0; i < 4; ++i)
#pragma unroll
    for (int j = 0; j < 4; ++j) acc[i][j] = f32x4{0.f, 0.f, 0.f, 0.f};

  const int nk = K >> 5;
  for (int kt = 0; kt < nk; ++kt) {
    const u16* ga = Ab + (size_t)r0 * K + kt * 32 + ko;
    const u16* gb = Bb + (size_t)r0 * K + kt * 32 + ko;
    load_lds16(ga, ldsA);
    load_lds16(ga + (size_t)64 * K, ldsA + 64 * 32);
    load_lds16(gb, ldsB);
    load_lds16(gb + (size_t)64 * K, ldsB + 64 * 32);
    __syncthreads();
    u16x8 af[4], bf[4];
#pragma unroll
    for (int i = 0; i < 4; ++i)
      af[i] = *(const u16x8*)(Alds + (wrow + 16 * i + l15) * 32 + quad * 8);
#pragma unroll
    for (int j = 0; j < 4; ++j)
      bf[j] = *(const u16x8*)(Blds + (wcol + 16 * j + l15) * 32 + quad * 8);
#pragma unroll
    for (int i = 0; i < 4; ++i)
#pragma unroll
      for (int j = 0; j < 4; ++j) acc[i][j] = mfma16(af[i], bf[j], acc[i][j]);
    __syncthreads();
  }

  const int gr = bm * 128 + wrow + quad * 4;
  const int gc = bn * 128 + wcol + l15;
#pragma unroll
  for (int i = 0; i < 4; ++i) {
#pragma unroll
    for (int j = 0; j < 4; ++j) {
      const int col = gc + 16 * j;
      float bs = 0.f;
      if (bias != nullptr && col < biasN) bs = bias[col];
#pragma unroll
      for (int r = 0; r < 4; ++r) {
        const int rowg = gr + 16 * i + r;
        float v = acc[i][j][r] + bs;
        if constexpr (MODE == 0) {
          ((u16*)Cout)[(size_t)rowg * ldc + col] = f2bf(v);
        } else {
          float o = resid[(size_t)rowg * 1024 + col] + v * lsg[col];
          ((float*)Cout)[(size_t)rowg * ldc + col] = o;
        }
      }
    }
  }
}

// ---------------- qkv extraction + per-head LN on q,k. One wave = one 64-vec.
__global__ __launch_bounds__(256) void k_qkv(const u16* __restrict__ f1,
                                             const float* __restrict__ qg,
                                             const float* __restrict__ qbb,
                                             const float* __restrict__ kg,
                                             const float* __restrict__ kbb,
                                             u16* __restrict__ q, u16* __restrict__ k,
                                             u16* __restrict__ v) {
  const int lane = threadIdx.x & 63;
  const int vi = blockIdx.x * 4 + (threadIdx.x >> 6);
  const int row = vi / 48;
  const int rem = vi - row * 48;
  const int which = rem >> 4, h = rem & 15;
  const float x = bf2f(f1[(size_t)row * 3840 + which * 1024 + h * 64 + lane]);
  const int b = row >> 10, npos = row & 1023;
  const size_t oidx = ((size_t)(b * 16 + h) * 1024 + npos) * 64 + lane;
  if (which == 2) { v[oidx] = f2bf(x); return; }
  float s = x;
#pragma unroll
  for (int off = 1; off < 64; off <<= 1) s += __shfl_xor(s, off);
  const float mean = s * (1.f / 64.f);
  const float d = x - mean;
  float ss = d * d;
#pragma unroll
  for (int off = 1; off < 64; off <<= 1) ss += __shfl_xor(ss, off);
  const float rstd = rsqrtf(ss * (1.f / 64.f) + 1e-5f);
  const float* g = (which == 0) ? qg : kg;
  const float* bb = (which == 0) ? qbb : kbb;
  const float val = d * rstd * g[lane] + bb[lane];
  u16* dst = (which == 0) ? q : k;
  dst[oidx] = f2bf(val);
}

// ---------------- exact gelu on mlp_hidden cols, zero-padded 716->768
__global__ __launch_bounds__(256) void k_gelu(const u16* __restrict__ f1,
                                              u16* __restrict__ out) {
  const int row = blockIdx.x;
#pragma unroll
  for (int c = threadIdx.x; c < 768; c += 256) {
    float r = 0.f;
    if (c < 716) {
      float xv = bf2f(f1[(size_t)row * 3840 + 3072 + c]);
      r = 0.5f * xv * (1.f + erff(xv * 0.70710678118654752f));
    }
    out[(size_t)row * 768 + c] = f2bf(r);
  }
}

// ---------------- flash attention: grid(8 qtiles, 64 bh), block 256 (4 waves)
// q,k: [bh][1024][64] bf16 ; vt: [bh][64][1024] bf16 ; xo: [4096][1024] bf16
__global__ __launch_bounds__(256) void k_flash(const u16* __restrict__ q,
                                               const u16* __restrict__ k,
                                               const u16* __restrict__ vt,
                                               u16* __restrict__ xo) {
  __shared__ __align__(16) u16 Kl[64 * 72];
  __shared__ __align__(16) u16 Vl[64 * 72];
  __shared__ __align__(16) u16 Pl[128 * 72];
  const int tid = threadIdx.x, wave = tid >> 6, lane = tid & 63;
  const int l15 = lane & 15, quad = lane >> 4;
  const int qt = blockIdx.x, bh = blockIdx.y;
  const int mrow = wave * 32;
  const u16* qb = q + ((size_t)bh * 1024 + qt * 128) * 64;
  const u16* kb = k + (size_t)bh * 1024 * 64;
  const u16* vb = vt + (size_t)bh * 64 * 1024;

#pragma unroll
  for (int p = 0; p < 4; ++p) {
    int ci = p * 256 + tid;
    int r = ci >> 3, db = (ci & 7) * 8;
    *(u16x8*)(Pl + r * 72 + db) = *(const u16x8*)(qb + (size_t)r * 64 + db);
  }
  __syncthreads();
  u16x8 qf[2][2];
#pragma unroll
  for (int i = 0; i < 2; ++i)
#pragma unroll
    for (int kk = 0; kk < 2; ++kk)
      qf[i][kk] = *(const u16x8*)(Pl + (mrow + 16 * i + l15) * 72 + kk * 32 + quad * 8);
  __syncthreads();

  f32x4 O[2][4];
  float mrun[2][4], lrun[2][4];
#pragma unroll
  for (int i = 0; i < 2; ++i)
#pragma unroll
    for (int j = 0; j < 4; ++j) O[i][j] = f32x4{0.f, 0.f, 0.f, 0.f};
#pragma unroll
  for (int i = 0; i < 2; ++i)
#pragma unroll
    for (int r = 0; r < 4; ++r) { mrun[i][r] = -1e30f; lrun[i][r] = 0.f; }

  for (int kv = 0; kv < 16; ++kv) {
#pragma unroll
    for (int p = 0; p < 2; ++p) {
      int ci = p * 256 + tid;
      int r = ci >> 3, db = (ci & 7) * 8;
      *(u16x8*)(Kl + r * 72 + db) =
          *(const u16x8*)(kb + (size_t)(kv * 64 + r) * 64 + db);
      *(u16x8*)(Vl + r * 72 + db) =
          *(const u16x8*)(vb + (size_t)r * 1024 + kv * 64 + db);
    }
    __syncthreads();
    f32x4 S[2][4];
#pragma unroll
    for (int i = 0; i < 2; ++i)
#pragma unroll
      for (int j = 0; j < 4; ++j) S[i][j] = f32x4{0.f, 0.f, 0.f, 0.f};
#pragma unroll
    for (int j = 0; j < 4; ++j)
#pragma unroll
      for (int kk = 0; kk < 2; ++kk) {
        u16x8 bf = *(const u16x8*)(Kl + (16 * j + l15) * 72 + kk * 32 + quad * 8);
        S[0][j] = mfma16(qf[0][kk], bf, S[0][j]);
        S[1][j] = mfma16(qf[1][kk], bf, S[1][j]);
      }
    constexpr float scale = 0.125f;  // 1/sqrt(64)
#pragma unroll
    for (int i = 0; i < 2; ++i)
#pragma unroll
      for (int r = 0; r < 4; ++r) {
        float mv = fmaxf(fmaxf(S[i][0][r], S[i][1][r]), fmaxf(S[i][2][r], S[i][3][r]));
#pragma unroll
        for (int off = 1; off < 16; off <<= 1) mv = fmaxf(mv, __shfl_xor(mv, off));
        mv *= scale;
        float mn = fmaxf(mrun[i][r], mv);
        float alpha = __expf(mrun[i][r] - mn);
        mrun[i][r] = mn;
        float rs = 0.f;
#pragma unroll
        for (int j = 0; j < 4; ++j) {
          float pv = __expf(S[i][j][r] * scale - mn);
          S[i][j][r] = pv;
          rs += pv;
        }
#pragma unroll
        for (int off = 1; off < 16; off <<= 1) rs += __shfl_xor(rs, off);
        lrun[i][r] = lrun[i][r] * alpha + rs;
#pragma unroll
        for (int jd = 0; jd < 4; ++jd) O[i][jd][r] *= alpha;
      }
    // P (bf16) to LDS in A-operand-readable layout; each wave touches only its rows
#pragma unroll
    for (int i = 0; i < 2; ++i)
#pragma unroll
      for (int j = 0; j < 4; ++j)
#pragma unroll
        for (int r = 0; r < 4; ++r)
          Pl[(mrow + 16 * i + quad * 4 + r) * 72 + 16 * j + l15] = f2bf(S[i][j][r]);
    __syncthreads();
#pragma unroll
    for (int c = 0; c < 2; ++c) {
      u16x8 pa0 = *(const u16x8*)(Pl + (mrow + l15) * 72 + c * 32 + quad * 8);
      u16x8 pa1 = *(const u16x8*)(Pl + (mrow + 16 + l15) * 72 + c * 32 + quad * 8);
#pragma unroll
      for (int jd = 0; jd < 4; ++jd) {
        u16x8 vf = *(const u16x8*)(Vl + (16 * jd + l15) * 72 + c * 32 + quad * 8);
        O[0][jd] = mfma16(pa0, vf, O[0][jd]);
        O[1][jd] = mfma16(pa1, vf, O[1][jd]);
      }
    }
    __syncthreads();
  }
  const int b = bh >> 4, h = bh & 15;
#pragma unroll
  for (int i = 0; i < 2; ++i)
#pragma unroll
    for (int r = 0; r < 4; ++r) {
      const int lr = mrow + 16 * i + quad * 4 + r;
      const float inv = 1.f / lrun[i][r];
      u16* orow = xo + (size_t)(b * 1024 + qt * 128 + lr) * 1024 + h * 64;
#pragma unroll
      for (int jd = 0; jd < 4; ++jd)
        orow[16 * jd + l15] = f2bf(O[i][jd][r] * inv);
    }
}

extern "C" void kernel_launch(void* const* d_in, const int* in_sizes, int n_in,
                              void* d_out, int out_size, void* d_ws, size_t ws_size,
                              hipStream_t stream) {
  (void)in_sizes; (void)n_in; (void)out_size; (void)ws_size;
  const float* x      = (const float*)d_in[0];
  const float* norm_g = (const float*)d_in[1];
  const float* norm_b = (const float*)d_in[2];
  const float* W1     = (const float*)d_in[3];
  const float* b1     = (const float*)d_in[4];
  const float* qn_g   = (const float*)d_in[5];
  const float* qn_b   = (const float*)d_in[6];
  const float* kn_g   = (const float*)d_in[7];
  const float* kn_b   = (const float*)d_in[8];
  const float* projW  = (const float*)d_in[9];
  const float* projb  = (const float*)d_in[10];
  const float* mlpW   = (const float*)d_in[11];
  const float* W2     = (const float*)d_in[12];
  const float* b2     = (const float*)d_in[13];
  const float* ls_g   = (const float*)d_in[14];

  char* ws = (char*)d_ws;
  // region layout (bytes); reuse: nx -> vbuf -> xo ; f1 -> comb
  u16* W1t  = (u16*)(ws + 0);          // [3840][1024]  7,864,320
  u16* pWt  = (u16*)(ws + 7864320);    // [1024][1024]  2,097,152
  u16* mWt  = (u16*)(ws + 9961472);    // [1024][768]   1,572,864
  u16* W2t  = (u16*)(ws + 11534336);   // [1024][2048]  4,194,304
  u16* nx   = (u16*)(ws + 15728640);   // [4096][1024]  8,388,608 (also vbuf, then xo)
  u16* f1   = (u16*)(ws + 24117248);   // [4096][3840] 31,457,280 (also comb [4096][2048])
  u16* qbuf = (u16*)(ws + 55574528);   // [64][1024][64] 8,388,608
  u16* kbuf = (u16*)(ws + 63963136);   // [64][1024][64] 8,388,608
  u16* vtb  = (u16*)(ws + 72351744);   // [64][64][1024] 8,388,608
  u16* gel  = (u16*)(ws + 80740352);   // [4096][768]   6,291,456  (end: 87,031,808)

  // 1. weights -> bf16 transposed [N][K], zero-padded
  k_trcvt<<<dim3(120, 32), 256, 0, stream>>>(W1, W1t, 1024, 3788, 1024, 3840);
  k_trcvt<<<dim3(32, 32), 256, 0, stream>>>(projW, pWt, 1024, 1024, 1024, 1024);
  k_trcvt<<<dim3(32, 24), 256, 0, stream>>>(mlpW, mWt, 716, 1024, 768, 1024);
  k_trcvt<<<dim3(32, 64), 256, 0, stream>>>(W2, W2t, 2048, 1024, 2048, 1024);
  // 2. LN(x)
  k_lnx<<<4096, 256, 0, stream>>>(x, norm_g, norm_b, nx);
  // 3. f1 = norm_x @ W1 + b1   (N padded to 3840)
  k_gemm<0><<<dim3(30, 32), 256, 0, stream>>>(nx, W1t, 1024, f1, 3840, b1, 3788,
                                              nullptr, nullptr);
  // 4. split qkv (+ q/k LN), gelu(mlp_hidden)
  k_qkv<<<49152, 256, 0, stream>>>(f1, qn_g, qn_b, kn_g, kn_b, qbuf, kbuf, nx);
  k_gelu<<<4096, 256, 0, stream>>>(f1, gel);
  // 5. V -> [bh][d][npos]
  k_trbf<<<dim3(2, 32, 64), 256, 0, stream>>>(nx, vtb, 1024, 64);
  // 6. attention
  k_flash<<<dim3(8, 64), 256, 0, stream>>>(qbuf, kbuf, vtb, nx);
  // 7. combined[:, :1024] = xo @ projW + projb ; combined[:, 1024:] = gelu @ mlpW
  k_gemm<0><<<dim3(8, 32), 256, 0, stream>>>(nx, pWt, 1024, f1, 2048, projb, 1024,
                                             nullptr, nullptr);
  k_gemm<0><<<dim3(8, 32), 256, 0, stream>>>(gel, mWt, 768, f1 + 1024, 2048, nullptr,
                                             0, nullptr, nullptr);
  // 8. out = x + (combined @ W2 + b2) * ls_g
  k_gemm<1><<<dim3(8, 32), 256, 0, stream>>>(f1, W2t, 2048, d_out, 1024, b2, 1024, x,
                                             ls_g);
}

// Round 3
// 326.291 us; speedup vs baseline: 1.2535x; 1.2535x over previous
//
#include <hip/hip_runtime.h>
#include <cstdint>
#include <cstddef>

typedef unsigned short u16;
typedef __attribute__((ext_vector_type(8))) u16 u16x8;
typedef __attribute__((ext_vector_type(8))) __bf16 bf16x8;
typedef __attribute__((ext_vector_type(4))) float f32x4;

__device__ __forceinline__ u16 f2bf(float f) {
  unsigned u = __builtin_bit_cast(unsigned, f);
  return (u16)((u + 0x7FFFu + ((u >> 16) & 1u)) >> 16);
}
__device__ __forceinline__ float bf2f(u16 h) {
  return __builtin_bit_cast(float, (unsigned)h << 16);
}
__device__ __forceinline__ f32x4 mfma16(u16x8 a, u16x8 b, f32x4 c) {
  return __builtin_amdgcn_mfma_f32_16x16x32_bf16(
      __builtin_bit_cast(bf16x8, a), __builtin_bit_cast(bf16x8, b), c, 0, 0, 0);
}
__device__ __forceinline__ void load_lds16(const void* g, void* l) {
  __builtin_amdgcn_global_load_lds(
      (const __attribute__((address_space(1))) void*)g,
      (__attribute__((address_space(3))) void*)l, 16, 0, 0);
}

// ---------------- transpose + fp32->bf16 convert: dst[n][k] = src[k][n], zero-padded
__global__ __launch_bounds__(256) void k_trcvt(const float* __restrict__ src,
                                               u16* __restrict__ dst,
                                               int R, int C, int dR, int dC) {
  __shared__ float t[32][33];
  const int n0 = blockIdx.x * 32, k0 = blockIdx.y * 32;
  const int tx = threadIdx.x & 31, ty = threadIdx.x >> 5;
#pragma unroll
  for (int j = 0; j < 4; ++j) {
    int kk = k0 + ty + 8 * j, nn = n0 + tx;
    float v = (kk < R && nn < C) ? src[(size_t)kk * C + nn] : 0.f;
    t[ty + 8 * j][tx] = v;
  }
  __syncthreads();
#pragma unroll
  for (int j = 0; j < 4; ++j) {
    int nn = n0 + ty + 8 * j, kk = k0 + tx;
    if (nn < dC && kk < dR) dst[(size_t)nn * dR + kk] = f2bf(t[tx][ty + 8 * j]);
  }
}

// ---------------- V^T extraction straight from f1: vtb[bh][d][n] = f1[b*1024+n][2048+h*64+d]
__global__ __launch_bounds__(256) void k_trvt(const u16* __restrict__ f1,
                                              u16* __restrict__ vtb) {
  __shared__ u16 t[32][33];
  const int z = blockIdx.z;           // bh
  const int b = z >> 4, h = z & 15;
  const int d0 = blockIdx.x * 32, n0 = blockIdx.y * 32;
  const int tx = threadIdx.x & 31, ty = threadIdx.x >> 5;
#pragma unroll
  for (int j = 0; j < 4; ++j)
    t[ty + 8 * j][tx] =
        f1[(size_t)(b * 1024 + n0 + ty + 8 * j) * 3840 + 2048 + h * 64 + d0 + tx];
  __syncthreads();
#pragma unroll
  for (int j = 0; j < 4; ++j)
    vtb[(size_t)z * 65536 + (size_t)(d0 + ty + 8 * j) * 1024 + n0 + tx] =
        t[tx][ty + 8 * j];
}

// ---------------- LayerNorm over DIM=1024, fp32 in -> bf16 out
__global__ __launch_bounds__(256) void k_lnx(const float* __restrict__ x,
                                             const float* __restrict__ g,
                                             const float* __restrict__ b,
                                             u16* __restrict__ out) {
  const int row = blockIdx.x, tid = threadIdx.x;
  float4 v = ((const float4*)(x + (size_t)row * 1024))[tid];
  float s = v.x + v.y + v.z + v.w;
  float ss = v.x * v.x + v.y * v.y + v.z * v.z + v.w * v.w;
#pragma unroll
  for (int off = 1; off < 64; off <<= 1) {
    s += __shfl_xor(s, off);
    ss += __shfl_xor(ss, off);
  }
  __shared__ float red[8];
  const int wid = tid >> 6, lane = tid & 63;
  if (lane == 0) { red[wid] = s; red[4 + wid] = ss; }
  __syncthreads();
  s = red[0] + red[1] + red[2] + red[3];
  ss = red[4] + red[5] + red[6] + red[7];
  const float mean = s * (1.f / 1024.f);
  const float var = ss * (1.f / 1024.f) - mean * mean;
  const float rstd = rsqrtf(var + 1e-5f);
  float4 gv = ((const float4*)g)[tid];
  float4 bv = ((const float4*)b)[tid];
  unsigned o0 = f2bf((v.x - mean) * rstd * gv.x + bv.x);
  unsigned o1 = f2bf((v.y - mean) * rstd * gv.y + bv.y);
  unsigned o2 = f2bf((v.z - mean) * rstd * gv.z + bv.z);
  unsigned o3 = f2bf((v.w - mean) * rstd * gv.w + bv.w);
  uint2 pk;
  pk.x = o0 | (o1 << 16);
  pk.y = o2 | (o3 << 16);
  ((uint2*)(out + (size_t)row * 1024))[tid] = pk;
}

// ---------------- bf16 GEMM 128x128: C[M][N] = A[M][K] * Bt[N][K]^T
template <int MODE>
__global__ __launch_bounds__(256) void k_gemm(const u16* __restrict__ A,
                                              const u16* __restrict__ B, int K,
                                              void* __restrict__ Cout, int ldc,
                                              const float* __restrict__ bias, int biasN,
                                              const float* __restrict__ resid,
                                              const float* __restrict__ lsg) {
  __shared__ __align__(16) u16 Alds[128 * 32];
  __shared__ __align__(16) u16 Blds[128 * 32];
  const int tid = threadIdx.x;
  const int lane = tid & 63, wave = tid >> 6;
  const int l15 = lane & 15, quad = lane >> 4;
  const int wrow = (wave >> 1) * 64, wcol = (wave & 1) * 64;
  const int bm = blockIdx.y, bn = blockIdx.x;

  const u16* Ab = A + (size_t)bm * 128 * K;
  const u16* Bb = B + (size_t)bn * 128 * K;
  const int r0 = tid >> 2;
  const int ko = (tid & 3) * 8;
  u16* ldsA = Alds + tid * 8;
  u16* ldsB = Blds + tid * 8;

  f32x4 acc[4][4];
#pragma unroll
  for (int i = 0; i < 4; ++i)
#pragma unroll
    for (int j = 0; j < 4; ++j) acc[i][j] = f32x4{0.f, 0.f, 0.f, 0.f};

  const int nk = K >> 5;
  for (int kt = 0; kt < nk; ++kt) {
    const u16* ga = Ab + (size_t)r0 * K + kt * 32 + ko;
    const u16* gb = Bb + (size_t)r0 * K + kt * 32 + ko;
    load_lds16(ga, ldsA);
    load_lds16(ga + (size_t)64 * K, ldsA + 64 * 32);
    load_lds16(gb, ldsB);
    load_lds16(gb + (size_t)64 * K, ldsB + 64 * 32);
    __syncthreads();
    u16x8 af[4], bf[4];
#pragma unroll
    for (int i = 0; i < 4; ++i)
      af[i] = *(const u16x8*)(Alds + (wrow + 16 * i + l15) * 32 + quad * 8);
#pragma unroll
    for (int j = 0; j < 4; ++j)
      bf[j] = *(const u16x8*)(Blds + (wcol + 16 * j + l15) * 32 + quad * 8);
#pragma unroll
    for (int i = 0; i < 4; ++i)
#pragma unroll
      for (int j = 0; j < 4; ++j) acc[i][j] = mfma16(af[i], bf[j], acc[i][j]);
    __syncthreads();
  }

  const int gr = bm * 128 + wrow + quad * 4;
  const int gc = bn * 128 + wcol + l15;
#pragma unroll
  for (int i = 0; i < 4; ++i) {
#pragma unroll
    for (int j = 0; j < 4; ++j) {
      const int col = gc + 16 * j;
      float bs = 0.f;
      if (bias != nullptr && col < biasN) bs = bias[col];
#pragma unroll
      for (int r = 0; r < 4; ++r) {
        const int rowg = gr + 16 * i + r;
        float v = acc[i][j][r] + bs;
        if constexpr (MODE == 0) {
          ((u16*)Cout)[(size_t)rowg * ldc + col] = f2bf(v);
        } else {
          float o = resid[(size_t)rowg * 1024 + col] + v * lsg[col];
          ((float*)Cout)[(size_t)rowg * ldc + col] = o;
        }
      }
    }
  }
}

// ---------------- bf16 GEMM 128x64 tile (higher occupancy for small-N GEMMs)
template <int MODE>
__global__ __launch_bounds__(256) void k_gemm64(const u16* __restrict__ A,
                                                const u16* __restrict__ B, int K,
                                                void* __restrict__ Cout, int ldc,
                                                const float* __restrict__ bias,
                                                const float* __restrict__ resid,
                                                const float* __restrict__ lsg) {
  __shared__ __align__(16) u16 Alds[128 * 32];
  __shared__ __align__(16) u16 Blds[64 * 32];
  const int tid = threadIdx.x;
  const int lane = tid & 63, wave = tid >> 6;
  const int l15 = lane & 15, quad = lane >> 4;
  const int wrow = wave * 32;
  const int bm = blockIdx.y, bn = blockIdx.x;

  const u16* Ab = A + (size_t)bm * 128 * K;
  const u16* Bb = B + (size_t)bn * 64 * K;
  u16* ldsA = Alds + tid * 8;
  u16* ldsB = Blds + tid * 8;
  const int ra = tid >> 2, koa = (tid & 3) * 8;

  f32x4 acc[2][4];
#pragma unroll
  for (int i = 0; i < 2; ++i)
#pragma unroll
    for (int j = 0; j < 4; ++j) acc[i][j] = f32x4{0.f, 0.f, 0.f, 0.f};

  const int nk = K >> 5;
  for (int kt = 0; kt < nk; ++kt) {
    const u16* ga = Ab + (size_t)ra * K + kt * 32 + koa;
    load_lds16(ga, ldsA);
    load_lds16(ga + (size_t)64 * K, ldsA + 64 * 32);
    load_lds16(Bb + (size_t)ra * K + kt * 32 + koa, ldsB);
    __syncthreads();
    u16x8 af[2], bf[4];
#pragma unroll
    for (int i = 0; i < 2; ++i)
      af[i] = *(const u16x8*)(Alds + (wrow + 16 * i + l15) * 32 + quad * 8);
#pragma unroll
    for (int j = 0; j < 4; ++j)
      bf[j] = *(const u16x8*)(Blds + (16 * j + l15) * 32 + quad * 8);
#pragma unroll
    for (int i = 0; i < 2; ++i)
#pragma unroll
      for (int j = 0; j < 4; ++j) acc[i][j] = mfma16(af[i], bf[j], acc[i][j]);
    __syncthreads();
  }

  const int gr = bm * 128 + wrow + quad * 4;
  const int gc = bn * 64 + l15;
#pragma unroll
  for (int i = 0; i < 2; ++i) {
#pragma unroll
    for (int j = 0; j < 4; ++j) {
      const int col = gc + 16 * j;
      float bs = (bias != nullptr) ? bias[col] : 0.f;
#pragma unroll
      for (int r = 0; r < 4; ++r) {
        const int rowg = gr + 16 * i + r;
        float v = acc[i][j][r] + bs;
        if constexpr (MODE == 0) {
          ((u16*)Cout)[(size_t)rowg * ldc + col] = f2bf(v);
        } else {
          float o = resid[(size_t)rowg * 1024 + col] + v * lsg[col];
          ((float*)Cout)[(size_t)rowg * ldc + col] = o;
        }
      }
    }
  }
}

// ---------------- q/k extraction + per-head LN, vectorized: block = one row's q+k
__global__ __launch_bounds__(256) void k_qkv(const u16* __restrict__ f1,
                                             const float* __restrict__ qg,
                                             const float* __restrict__ qbb,
                                             const float* __restrict__ kg,
                                             const float* __restrict__ kbb,
                                             u16* __restrict__ q,
                                             u16* __restrict__ k) {
  const int row = blockIdx.x, tid = threadIdx.x;
  const int rem = tid >> 3;           // vec index in row: 0..31
  const int which = rem >> 4, h = rem & 15;
  const int e8 = (tid & 7) * 8;
  u16x8 xv = *(const u16x8*)(f1 + (size_t)row * 3840 + which * 1024 + h * 64 + e8);
  float xf[8];
  float s1 = 0.f, s2 = 0.f;
#pragma unroll
  for (int e = 0; e < 8; ++e) {
    xf[e] = bf2f(xv[e]);
    s1 += xf[e];
    s2 += xf[e] * xf[e];
  }
#pragma unroll
  for (int off = 1; off < 8; off <<= 1) {
    s1 += __shfl_xor(s1, off);
    s2 += __shfl_xor(s2, off);
  }
  const float mean = s1 * (1.f / 64.f);
  const float var = s2 * (1.f / 64.f) - mean * mean;
  const float rstd = rsqrtf(var + 1e-5f);
  const float* g = (which == 0) ? qg : kg;
  const float* bb = (which == 0) ? qbb : kbb;
  float4 g0 = ((const float4*)g)[e8 >> 2], g1 = ((const float4*)g)[(e8 >> 2) + 1];
  float4 b0 = ((const float4*)bb)[e8 >> 2], b1 = ((const float4*)bb)[(e8 >> 2) + 1];
  float gv[8] = {g0.x, g0.y, g0.z, g0.w, g1.x, g1.y, g1.z, g1.w};
  float bv[8] = {b0.x, b0.y, b0.z, b0.w, b1.x, b1.y, b1.z, b1.w};
  u16x8 o;
#pragma unroll
  for (int e = 0; e < 8; ++e) o[e] = f2bf((xf[e] - mean) * rstd * gv[e] + bv[e]);
  const int b = row >> 10, n = row & 1023;
  u16* dst = (which == 0) ? q : k;
  *(u16x8*)(dst + ((size_t)(b * 16 + h) * 1024 + n) * 64 + e8) = o;
}

// ---------------- exact gelu, vectorized, zero-padded 716->768
__global__ __launch_bounds__(256) void k_gelu(const u16* __restrict__ f1,
                                              u16* __restrict__ out) {
  const int id = blockIdx.x * 256 + threadIdx.x;
  const int row = id / 96, c8 = id - row * 96;
  u16x8 xv = *(const u16x8*)(f1 + (size_t)row * 3840 + 3072 + c8 * 8);
  u16x8 o;
#pragma unroll
  for (int e = 0; e < 8; ++e) {
    const int col = c8 * 8 + e;
    float r = 0.f;
    if (col < 716) {
      float x = bf2f(xv[e]);
      r = 0.5f * x * (1.f + erff(x * 0.70710678118654752f));
    }
    o[e] = f2bf(r);
  }
  *(u16x8*)(out + (size_t)row * 768 + c8 * 8) = o;
}

// ---------------- flash attention, no-max softmax, Q-tile 64, grid 1024 linear
// q,k: [bh][1024][64] bf16 ; vt: [bh][64][1024] bf16 ; xo: [4096][1024] bf16
__global__ __launch_bounds__(256) void k_flash(const u16* __restrict__ q,
                                               const u16* __restrict__ k,
                                               const u16* __restrict__ vt,
                                               u16* __restrict__ xo) {
  __shared__ __align__(16) u16 Kl[64 * 72];
  __shared__ __align__(16) u16 Vl[64 * 72];
  __shared__ __align__(16) u16 Pl[4 * 16 * 72];
  const int tid = threadIdx.x, wave = tid >> 6, lane = tid & 63;
  const int l15 = lane & 15, quad = lane >> 4;
  // XCD swizzle: all 16 q-tiles of one bh land on the same XCD (L%8 constant)
  const int L = blockIdx.x;
  const int xcd = L & 7, idx = L >> 3;
  const int bh = xcd * 8 + (idx & 7), qt = idx >> 3;
  const int qrow0 = qt * 64 + wave * 16;
  const u16* qb = q + ((size_t)bh * 1024 + qrow0) * 64;
  const u16* kb = k + (size_t)bh * 1024 * 64;
  const u16* vb = vt + (size_t)bh * 64 * 1024;
  u16* Pw = Pl + wave * 16 * 72;

  u16x8 qf[2];
#pragma unroll
  for (int kk = 0; kk < 2; ++kk)
    qf[kk] = *(const u16x8*)(qb + (size_t)l15 * 64 + kk * 32 + quad * 8);

  f32x4 O[4];
  float lacc[4] = {0.f, 0.f, 0.f, 0.f};
#pragma unroll
  for (int dt = 0; dt < 4; ++dt) O[dt] = f32x4{0.f, 0.f, 0.f, 0.f};

  for (int kv = 0; kv < 16; ++kv) {
#pragma unroll
    for (int p = 0; p < 2; ++p) {
      const int ci = p * 256 + tid;
      const int r = ci >> 3, off = (ci & 7) * 8;
      *(u16x8*)(Kl + r * 72 + off) =
          *(const u16x8*)(kb + (size_t)(kv * 64 + r) * 64 + off);
      *(u16x8*)(Vl + r * 72 + off) =
          *(const u16x8*)(vb + (size_t)r * 1024 + kv * 64 + off);
    }
    __syncthreads();
    f32x4 S[4];
#pragma unroll
    for (int j = 0; j < 4; ++j) S[j] = f32x4{0.f, 0.f, 0.f, 0.f};
#pragma unroll
    for (int j = 0; j < 4; ++j)
#pragma unroll
      for (int kk = 0; kk < 2; ++kk) {
        u16x8 bfr = *(const u16x8*)(Kl + (16 * j + l15) * 72 + kk * 32 + quad * 8);
        S[j] = mfma16(qf[kk], bfr, S[j]);
      }
    // no-max softmax: scores bounded (|s|<=8 after q/k LN), exp safe in fp32
#pragma unroll
    for (int j = 0; j < 4; ++j)
#pragma unroll
      for (int r = 0; r < 4; ++r) {
        float pv = __expf(S[j][r] * 0.125f);
        lacc[r] += pv;
        Pw[(quad * 4 + r) * 72 + 16 * j + l15] = f2bf(pv);
      }
    __syncthreads();  // make P writes visible/ordered before b128 reads
#pragma unroll
    for (int c = 0; c < 2; ++c) {
      u16x8 pa = *(const u16x8*)(Pw + l15 * 72 + c * 32 + quad * 8);
#pragma unroll
      for (int dt = 0; dt < 4; ++dt) {
        u16x8 vf = *(const u16x8*)(Vl + (16 * dt + l15) * 72 + c * 32 + quad * 8);
        O[dt] = mfma16(pa, vf, O[dt]);
      }
    }
    __syncthreads();
  }
#pragma unroll
  for (int r = 0; r < 4; ++r) {
#pragma unroll
    for (int off = 1; off < 16; off <<= 1) lacc[r] += __shfl_xor(lacc[r], off);
  }
  const int b = bh >> 4, h = bh & 15;
#pragma unroll
  for (int r = 0; r < 4; ++r) {
    const float inv = 1.f / lacc[r];
    u16* orow = xo + (size_t)(b * 1024 + qrow0 + quad * 4 + r) * 1024 + h * 64;
#pragma unroll
    for (int dt = 0; dt < 4; ++dt) orow[16 * dt + l15] = f2bf(O[dt][r] * inv);
  }
}

extern "C" void kernel_launch(void* const* d_in, const int* in_sizes, int n_in,
                              void* d_out, int out_size, void* d_ws, size_t ws_size,
                              hipStream_t stream) {
  (void)in_sizes; (void)n_in; (void)out_size; (void)ws_size;
  const float* x      = (const float*)d_in[0];
  const float* norm_g = (const float*)d_in[1];
  const float* norm_b = (const float*)d_in[2];
  const float* W1     = (const float*)d_in[3];
  const float* b1     = (const float*)d_in[4];
  const float* qn_g   = (const float*)d_in[5];
  const float* qn_b   = (const float*)d_in[6];
  const float* kn_g   = (const float*)d_in[7];
  const float* kn_b   = (const float*)d_in[8];
  const float* projW  = (const float*)d_in[9];
  const float* projb  = (const float*)d_in[10];
  const float* mlpW   = (const float*)d_in[11];
  const float* W2     = (const float*)d_in[12];
  const float* b2     = (const float*)d_in[13];
  const float* ls_g   = (const float*)d_in[14];

  char* ws = (char*)d_ws;
  u16* W1t  = (u16*)(ws + 0);          // [3840][1024]  7,864,320
  u16* pWt  = (u16*)(ws + 7864320);    // [1024][1024]  2,097,152
  u16* mWt  = (u16*)(ws + 9961472);    // [1024][768]   1,572,864
  u16* W2t  = (u16*)(ws + 11534336);   // [1024][2048]  4,194,304
  u16* nx   = (u16*)(ws + 15728640);   // [4096][1024]  8,388,608 (then xo)
  u16* f1   = (u16*)(ws + 24117248);   // [4096][3840] 31,457,280 (then comb [4096][2048])
  u16* qbuf = (u16*)(ws + 55574528);   // [64][1024][64] 8,388,608
  u16* kbuf = (u16*)(ws + 63963136);   // [64][1024][64] 8,388,608
  u16* vtb  = (u16*)(ws + 72351744);   // [64][64][1024] 8,388,608
  u16* gel  = (u16*)(ws + 80740352);   // [4096][768]   6,291,456

  k_trcvt<<<dim3(120, 32), 256, 0, stream>>>(W1, W1t, 1024, 3788, 1024, 3840);
  k_trcvt<<<dim3(32, 32), 256, 0, stream>>>(projW, pWt, 1024, 1024, 1024, 1024);
  k_trcvt<<<dim3(32, 24), 256, 0, stream>>>(mlpW, mWt, 716, 1024, 768, 1024);
  k_trcvt<<<dim3(32, 64), 256, 0, stream>>>(W2, W2t, 2048, 1024, 2048, 1024);
  k_lnx<<<4096, 256, 0, stream>>>(x, norm_g, norm_b, nx);
  k_gemm<0><<<dim3(30, 32), 256, 0, stream>>>(nx, W1t, 1024, f1, 3840, b1, 3788,
                                              nullptr, nullptr);
  k_qkv<<<4096, 256, 0, stream>>>(f1, qn_g, qn_b, kn_g, kn_b, qbuf, kbuf);
  k_gelu<<<1536, 256, 0, stream>>>(f1, gel);
  k_trvt<<<dim3(2, 32, 64), 256, 0, stream>>>(f1, vtb);
  k_flash<<<1024, 256, 0, stream>>>(qbuf, kbuf, vtb, nx);
  k_gemm64<0><<<dim3(16, 32), 256, 0, stream>>>(nx, pWt, 1024, f1, 2048, projb,
                                                nullptr, nullptr);
  k_gemm64<0><<<dim3(16, 32), 256, 0, stream>>>(gel, mWt, 768, f1 + 1024, 2048,
                                                nullptr, nullptr, nullptr);
  k_gemm64<1><<<dim3(16, 32), 256, 0, stream>>>(f1, W2t, 2048, d_out, 1024, b2, x,
                                                ls_g);
}

// Round 5
// 288.292 us; speedup vs baseline: 1.4188x; 1.1318x over previous
//
#include <hip/hip_runtime.h>
#include <cstdint>
#include <cstddef>

typedef unsigned short u16;
typedef __attribute__((ext_vector_type(8))) u16 u16x8;
typedef __attribute__((ext_vector_type(8))) __bf16 bf16x8;
typedef __attribute__((ext_vector_type(4))) float f32x4;

__device__ __forceinline__ u16 f2bf(float f) {
  unsigned u = __builtin_bit_cast(unsigned, f);
  return (u16)((u + 0x7FFFu + ((u >> 16) & 1u)) >> 16);
}
__device__ __forceinline__ float bf2f(u16 h) {
  return __builtin_bit_cast(float, (unsigned)h << 16);
}
__device__ __forceinline__ f32x4 mfma16(u16x8 a, u16x8 b, f32x4 c) {
  return __builtin_amdgcn_mfma_f32_16x16x32_bf16(
      __builtin_bit_cast(bf16x8, a), __builtin_bit_cast(bf16x8, b), c, 0, 0, 0);
}
__device__ __forceinline__ void load_lds16(const void* g, void* l) {
  __builtin_amdgcn_global_load_lds(
      (const __attribute__((address_space(1))) void*)g,
      (__attribute__((address_space(3))) void*)l, 16, 0, 0);
}

// ---------------- all 4 weight transposes fused: dst[n][k] = src[k][n], zero-padded
__global__ __launch_bounds__(256) void k_trcvt_all(
    const float* __restrict__ W1, const float* __restrict__ projW,
    const float* __restrict__ mlpW, const float* __restrict__ W2,
    u16* __restrict__ W1t, u16* __restrict__ pWt, u16* __restrict__ mWt,
    u16* __restrict__ W2t) {
  __shared__ float t[32][33];
  const int L = blockIdx.x;
  const float* src;
  u16* dst;
  int R, C, dR, dC, bx, by;
  if (L < 3840) {
    src = W1; dst = W1t; R = 1024; C = 3788; dR = 1024; dC = 3840;
    bx = L % 120; by = L / 120;
  } else if (L < 4864) {
    int tq = L - 3840;
    src = projW; dst = pWt; R = 1024; C = 1024; dR = 1024; dC = 1024;
    bx = tq & 31; by = tq >> 5;
  } else if (L < 5632) {
    int tq = L - 4864;
    src = mlpW; dst = mWt; R = 716; C = 1024; dR = 768; dC = 1024;
    bx = tq & 31; by = tq >> 5;
  } else {
    int tq = L - 5632;
    src = W2; dst = W2t; R = 2048; C = 1024; dR = 2048; dC = 1024;
    bx = tq & 31; by = tq >> 5;
  }
  const int n0 = bx * 32, k0 = by * 32;
  const int tx = threadIdx.x & 31, ty = threadIdx.x >> 5;
#pragma unroll
  for (int j = 0; j < 4; ++j) {
    int kk = k0 + ty + 8 * j, nn = n0 + tx;
    float v = (kk < R && nn < C) ? src[(size_t)kk * C + nn] : 0.f;
    t[ty + 8 * j][tx] = v;
  }
  __syncthreads();
#pragma unroll
  for (int j = 0; j < 4; ++j) {
    int nn = n0 + ty + 8 * j, kk = k0 + tx;
    if (nn < dC && kk < dR) dst[(size_t)nn * dR + kk] = f2bf(t[tx][ty + 8 * j]);
  }
}

// ---------------- V^T extraction straight from f1: vtb[bh][d][n] = f1[b*1024+n][2048+h*64+d]
__global__ __launch_bounds__(256) void k_trvt(const u16* __restrict__ f1,
                                              u16* __restrict__ vtb) {
  __shared__ u16 t[32][33];
  const int z = blockIdx.z;
  const int b = z >> 4, h = z & 15;
  const int d0 = blockIdx.x * 32, n0 = blockIdx.y * 32;
  const int tx = threadIdx.x & 31, ty = threadIdx.x >> 5;
#pragma unroll
  for (int j = 0; j < 4; ++j)
    t[ty + 8 * j][tx] =
        f1[(size_t)(b * 1024 + n0 + ty + 8 * j) * 3840 + 2048 + h * 64 + d0 + tx];
  __syncthreads();
#pragma unroll
  for (int j = 0; j < 4; ++j)
    vtb[(size_t)z * 65536 + (size_t)(d0 + ty + 8 * j) * 1024 + n0 + tx] =
        t[tx][ty + 8 * j];
}

// ---------------- LayerNorm over DIM=1024, fp32 in -> bf16 out
__global__ __launch_bounds__(256) void k_lnx(const float* __restrict__ x,
                                             const float* __restrict__ g,
                                             const float* __restrict__ b,
                                             u16* __restrict__ out) {
  const int row = blockIdx.x, tid = threadIdx.x;
  float4 v = ((const float4*)(x + (size_t)row * 1024))[tid];
  float s = v.x + v.y + v.z + v.w;
  float ss = v.x * v.x + v.y * v.y + v.z * v.z + v.w * v.w;
#pragma unroll
  for (int off = 1; off < 64; off <<= 1) {
    s += __shfl_xor(s, off);
    ss += __shfl_xor(ss, off);
  }
  __shared__ float red[8];
  const int wid = tid >> 6, lane = tid & 63;
  if (lane == 0) { red[wid] = s; red[4 + wid] = ss; }
  __syncthreads();
  s = red[0] + red[1] + red[2] + red[3];
  ss = red[4] + red[5] + red[6] + red[7];
  const float mean = s * (1.f / 1024.f);
  const float var = ss * (1.f / 1024.f) - mean * mean;
  const float rstd = rsqrtf(var + 1e-5f);
  float4 gv = ((const float4*)g)[tid];
  float4 bv = ((const float4*)b)[tid];
  unsigned o0 = f2bf((v.x - mean) * rstd * gv.x + bv.x);
  unsigned o1 = f2bf((v.y - mean) * rstd * gv.y + bv.y);
  unsigned o2 = f2bf((v.z - mean) * rstd * gv.z + bv.z);
  unsigned o3 = f2bf((v.w - mean) * rstd * gv.w + bv.w);
  uint2 pk;
  pk.x = o0 | (o1 << 16);
  pk.y = o2 | (o3 << 16);
  ((uint2*)(out + (size_t)row * 1024))[tid] = pk;
}

// ---------------- bf16 GEMM 128x128, BK=64, XOR k-chunk swizzle (bank-conflict-free)
// LDS layout: row r's global k-chunk c (16B) stored at position c ^ (r&7).
// Staging keeps global_load_lds lane-contiguity: lane writes lds base+lane*16,
// sources the swizzled global chunk.
template <int MODE>
__global__ __launch_bounds__(256) void k_gemm(const u16* __restrict__ A,
                                              const u16* __restrict__ B, int K,
                                              void* __restrict__ Cout, int ldc,
                                              const float* __restrict__ bias, int biasN,
                                              const float* __restrict__ resid,
                                              const float* __restrict__ lsg) {
  __shared__ __align__(16) u16 Alds[128 * 64];
  __shared__ __align__(16) u16 Blds[128 * 64];
  const int tid = threadIdx.x;
  const int lane = tid & 63, wave = tid >> 6;
  const int l15 = lane & 15, quad = lane >> 4;
  const int wrow = (wave >> 1) * 64, wcol = (wave & 1) * 64;
  const int bm = blockIdx.y, bn = blockIdx.x;

  const u16* Ab = A + (size_t)bm * 128 * K;
  const u16* Bb = B + (size_t)bn * 128 * K;
  const int srow = tid >> 3;                       // 0..31
  const int schunk = tid & 7;                      // lds chunk position
  const int gch8 = (schunk ^ (srow & 7)) * 8;      // swizzled global k offset (elems)

  f32x4 acc[4][4];
#pragma unroll
  for (int i = 0; i < 4; ++i)
#pragma unroll
    for (int j = 0; j < 4; ++j) acc[i][j] = f32x4{0.f, 0.f, 0.f, 0.f};

  const int nk = K >> 6;
  for (int kt = 0; kt < nk; ++kt) {
    const int kb = kt * 64 + gch8;
#pragma unroll
    for (int p = 0; p < 4; ++p) {
      load_lds16(Ab + (size_t)(srow + 32 * p) * K + kb,
                 Alds + (srow + 32 * p) * 64 + schunk * 8);
      load_lds16(Bb + (size_t)(srow + 32 * p) * K + kb,
                 Blds + (srow + 32 * p) * 64 + schunk * 8);
    }
    __syncthreads();
#pragma unroll
    for (int kk = 0; kk < 2; ++kk) {
      const int pch = ((kk * 4 + quad) ^ (l15 & 7)) * 8;
      u16x8 af[4], bf[4];
#pragma unroll
      for (int i = 0; i < 4; ++i)
        af[i] = *(const u16x8*)(Alds + (wrow + 16 * i + l15) * 64 + pch);
#pragma unroll
      for (int j = 0; j < 4; ++j)
        bf[j] = *(const u16x8*)(Blds + (wcol + 16 * j + l15) * 64 + pch);
#pragma unroll
      for (int i = 0; i < 4; ++i)
#pragma unroll
        for (int j = 0; j < 4; ++j) acc[i][j] = mfma16(af[i], bf[j], acc[i][j]);
    }
    __syncthreads();
  }

  const int gr = bm * 128 + wrow + quad * 4;
  const int gc = bn * 128 + wcol + l15;
#pragma unroll
  for (int i = 0; i < 4; ++i) {
#pragma unroll
    for (int j = 0; j < 4; ++j) {
      const int col = gc + 16 * j;
      float bs = 0.f;
      if (bias != nullptr && col < biasN) bs = bias[col];
#pragma unroll
      for (int r = 0; r < 4; ++r) {
        const int rowg = gr + 16 * i + r;
        float v = acc[i][j][r] + bs;
        if constexpr (MODE == 0) {
          ((u16*)Cout)[(size_t)rowg * ldc + col] = f2bf(v);
        } else {
          float o = resid[(size_t)rowg * 1024 + col] + v * lsg[col];
          ((float*)Cout)[(size_t)rowg * ldc + col] = o;
        }
      }
    }
  }
}

// ---------------- 128x64-tile GEMM core, BK=64 + swizzle (shared by pm/final)
__device__ __forceinline__ void gemm64_core(const u16* __restrict__ A,
                                            const u16* __restrict__ B, int K,
                                            u16* Alds, u16* Blds,
                                            f32x4 (&acc)[2][4], int tid) {
  const int lane = tid & 63, wave = tid >> 6;
  const int l15 = lane & 15, quad = lane >> 4;
  const int wrow = wave * 32;
  const int srow = tid >> 3, schunk = tid & 7;
  const int gch8 = (schunk ^ (srow & 7)) * 8;
  const int nk = K >> 6;
  for (int kt = 0; kt < nk; ++kt) {
    const int kb = kt * 64 + gch8;
#pragma unroll
    for (int p = 0; p < 4; ++p)
      load_lds16(A + (size_t)(srow + 32 * p) * K + kb,
                 Alds + (srow + 32 * p) * 64 + schunk * 8);
#pragma unroll
    for (int p = 0; p < 2; ++p)
      load_lds16(B + (size_t)(srow + 32 * p) * K + kb,
                 Blds + (srow + 32 * p) * 64 + schunk * 8);
    __syncthreads();
#pragma unroll
    for (int kk = 0; kk < 2; ++kk) {
      const int pch = ((kk * 4 + quad) ^ (l15 & 7)) * 8;
      u16x8 af[2], bf[4];
#pragma unroll
      for (int i = 0; i < 2; ++i)
        af[i] = *(const u16x8*)(Alds + (wrow + 16 * i + l15) * 64 + pch);
#pragma unroll
      for (int j = 0; j < 4; ++j)
        bf[j] = *(const u16x8*)(Blds + (16 * j + l15) * 64 + pch);
#pragma unroll
      for (int i = 0; i < 2; ++i)
#pragma unroll
        for (int j = 0; j < 4; ++j) acc[i][j] = mfma16(af[i], bf[j], acc[i][j]);
    }
    __syncthreads();
  }
}

// ---------------- proj + mlp GEMMs fused into one launch (disjoint comb halves)
__global__ __launch_bounds__(256) void k_gemm64_pm(
    const u16* __restrict__ xo, const u16* __restrict__ pWt,
    const u16* __restrict__ gel, const u16* __restrict__ mWt,
    u16* __restrict__ comb, const float* __restrict__ projb) {
  __shared__ __align__(16) u16 Alds[128 * 64];
  __shared__ __align__(16) u16 Blds[64 * 64];
  const int tid = threadIdx.x;
  const int bm = blockIdx.y, bnq = blockIdx.x;
  const u16* A;
  const u16* B;
  int K, colbase;
  const float* bias;
  if (bnq < 16) {
    A = xo + (size_t)bm * 128 * 1024;
    B = pWt + (size_t)bnq * 64 * 1024;
    K = 1024; colbase = bnq * 64; bias = projb;
  } else {
    const int bn = bnq - 16;
    A = gel + (size_t)bm * 128 * 768;
    B = mWt + (size_t)bn * 64 * 768;
    K = 768; colbase = 1024 + bn * 64; bias = nullptr;
  }
  f32x4 acc[2][4];
#pragma unroll
  for (int i = 0; i < 2; ++i)
#pragma unroll
    for (int j = 0; j < 4; ++j) acc[i][j] = f32x4{0.f, 0.f, 0.f, 0.f};
  gemm64_core(A, B, K, Alds, Blds, acc, tid);

  const int lane = tid & 63, wave = tid >> 6;
  const int l15 = lane & 15, quad = lane >> 4;
  const int gr = bm * 128 + wave * 32 + quad * 4;
#pragma unroll
  for (int i = 0; i < 2; ++i) {
#pragma unroll
    for (int j = 0; j < 4; ++j) {
      const int col = colbase + 16 * j + l15;
      const float bs = (bias != nullptr) ? bias[col] : 0.f;
#pragma unroll
      for (int r = 0; r < 4; ++r)
        comb[(size_t)(gr + 16 * i + r) * 2048 + col] = f2bf(acc[i][j][r] + bs);
    }
  }
}

// ---------------- final GEMM: out = x + (comb @ W2t^T + b2) * ls_g  (fp32 out)
__global__ __launch_bounds__(256) void k_gemm64f(const u16* __restrict__ comb,
                                                 const u16* __restrict__ W2t,
                                                 float* __restrict__ out,
                                                 const float* __restrict__ b2,
                                                 const float* __restrict__ x,
                                                 const float* __restrict__ lsg) {
  __shared__ __align__(16) u16 Alds[128 * 64];
  __shared__ __align__(16) u16 Blds[64 * 64];
  const int tid = threadIdx.x;
  const int bm = blockIdx.y, bn = blockIdx.x;
  f32x4 acc[2][4];
#pragma unroll
  for (int i = 0; i < 2; ++i)
#pragma unroll
    for (int j = 0; j < 4; ++j) acc[i][j] = f32x4{0.f, 0.f, 0.f, 0.f};
  gemm64_core(comb + (size_t)bm * 128 * 2048, W2t + (size_t)bn * 64 * 2048, 2048,
              Alds, Blds, acc, tid);

  const int lane = tid & 63, wave = tid >> 6;
  const int l15 = lane & 15, quad = lane >> 4;
  const int gr = bm * 128 + wave * 32 + quad * 4;
  const int gc = bn * 64 + l15;
#pragma unroll
  for (int i = 0; i < 2; ++i) {
#pragma unroll
    for (int j = 0; j < 4; ++j) {
      const int col = gc + 16 * j;
      const float bs = b2[col], ls = lsg[col];
#pragma unroll
      for (int r = 0; r < 4; ++r) {
        const int rowg = gr + 16 * i + r;
        out[(size_t)rowg * 1024 + col] =
            x[(size_t)rowg * 1024 + col] + (acc[i][j][r] + bs) * ls;
      }
    }
  }
}

// ---------------- q/k per-head LN + gelu, fused in one launch
__global__ __launch_bounds__(256) void k_qkvgelu(const u16* __restrict__ f1,
                                                 const float* __restrict__ qg,
                                                 const float* __restrict__ qbb,
                                                 const float* __restrict__ kg,
                                                 const float* __restrict__ kbb,
                                                 u16* __restrict__ q,
                                                 u16* __restrict__ k,
                                                 u16* __restrict__ gel) {
  const int tid = threadIdx.x;
  if (blockIdx.x < 4096) {
    const int row = blockIdx.x;
    const int rem = tid >> 3;
    const int which = rem >> 4, h = rem & 15;
    const int e8 = (tid & 7) * 8;
    u16x8 xv = *(const u16x8*)(f1 + (size_t)row * 3840 + which * 1024 + h * 64 + e8);
    float xf[8];
    float s1 = 0.f, s2 = 0.f;
#pragma unroll
    for (int e = 0; e < 8; ++e) {
      xf[e] = bf2f(xv[e]);
      s1 += xf[e];
      s2 += xf[e] * xf[e];
    }
#pragma unroll
    for (int off = 1; off < 8; off <<= 1) {
      s1 += __shfl_xor(s1, off);
      s2 += __shfl_xor(s2, off);
    }
    const float mean = s1 * (1.f / 64.f);
    const float var = s2 * (1.f / 64.f) - mean * mean;
    const float rstd = rsqrtf(var + 1e-5f);
    const float* g = (which == 0) ? qg : kg;
    const float* bb = (which == 0) ? qbb : kbb;
    float4 g0 = ((const float4*)g)[e8 >> 2], g1 = ((const float4*)g)[(e8 >> 2) + 1];
    float4 b0 = ((const float4*)bb)[e8 >> 2], b1 = ((const float4*)bb)[(e8 >> 2) + 1];
    float gv[8] = {g0.x, g0.y, g0.z, g0.w, g1.x, g1.y, g1.z, g1.w};
    float bv[8] = {b0.x, b0.y, b0.z, b0.w, b1.x, b1.y, b1.z, b1.w};
    u16x8 o;
#pragma unroll
    for (int e = 0; e < 8; ++e) o[e] = f2bf((xf[e] - mean) * rstd * gv[e] + bv[e]);
    const int b = row >> 10, n = row & 1023;
    u16* dst = (which == 0) ? q : k;
    *(u16x8*)(dst + ((size_t)(b * 16 + h) * 1024 + n) * 64 + e8) = o;
  } else {
    const int id = (blockIdx.x - 4096) * 256 + tid;
    const int row = id / 96, c8 = id - row * 96;
    u16x8 xv = *(const u16x8*)(f1 + (size_t)row * 3840 + 3072 + c8 * 8);
    u16x8 o;
#pragma unroll
    for (int e = 0; e < 8; ++e) {
      const int col = c8 * 8 + e;
      float r = 0.f;
      if (col < 716) {
        float xx = bf2f(xv[e]);
        r = 0.5f * xx * (1.f + erff(xx * 0.70710678118654752f));
      }
      o[e] = f2bf(r);
    }
    *(u16x8*)(gel + (size_t)row * 768 + c8 * 8) = o;
  }
}

// ---------------- flash attention, no-max softmax, Q-tile 64 (unchanged from R3)
__global__ __launch_bounds__(256) void k_flash(const u16* __restrict__ q,
                                               const u16* __restrict__ k,
                                               const u16* __restrict__ vt,
                                               u16* __restrict__ xo) {
  __shared__ __align__(16) u16 Kl[64 * 72];
  __shared__ __align__(16) u16 Vl[64 * 72];
  __shared__ __align__(16) u16 Pl[4 * 16 * 72];
  const int tid = threadIdx.x, wave = tid >> 6, lane = tid & 63;
  const int l15 = lane & 15, quad = lane >> 4;
  const int L = blockIdx.x;
  const int xcd = L & 7, idx = L >> 3;
  const int bh = xcd * 8 + (idx & 7), qt = idx >> 3;
  const int qrow0 = qt * 64 + wave * 16;
  const u16* qb = q + ((size_t)bh * 1024 + qrow0) * 64;
  const u16* kb = k + (size_t)bh * 1024 * 64;
  const u16* vb = vt + (size_t)bh * 64 * 1024;
  u16* Pw = Pl + wave * 16 * 72;

  u16x8 qf[2];
#pragma unroll
  for (int kk = 0; kk < 2; ++kk)
    qf[kk] = *(const u16x8*)(qb + (size_t)l15 * 64 + kk * 32 + quad * 8);

  f32x4 O[4];
  float lacc[4] = {0.f, 0.f, 0.f, 0.f};
#pragma unroll
  for (int dt = 0; dt < 4; ++dt) O[dt] = f32x4{0.f, 0.f, 0.f, 0.f};

  for (int kv = 0; kv < 16; ++kv) {
#pragma unroll
    for (int p = 0; p < 2; ++p) {
      const int ci = p * 256 + tid;
      const int r = ci >> 3, off = (ci & 7) * 8;
      *(u16x8*)(Kl + r * 72 + off) =
          *(const u16x8*)(kb + (size_t)(kv * 64 + r) * 64 + off);
      *(u16x8*)(Vl + r * 72 + off) =
          *(const u16x8*)(vb + (size_t)r * 1024 + kv * 64 + off);
    }
    __syncthreads();
    f32x4 S[4];
#pragma unroll
    for (int j = 0; j < 4; ++j) S[j] = f32x4{0.f, 0.f, 0.f, 0.f};
#pragma unroll
    for (int j = 0; j < 4; ++j)
#pragma unroll
      for (int kk = 0; kk < 2; ++kk) {
        u16x8 bfr = *(const u16x8*)(Kl + (16 * j + l15) * 72 + kk * 32 + quad * 8);
        S[j] = mfma16(qf[kk], bfr, S[j]);
      }
#pragma unroll
    for (int j = 0; j < 4; ++j)
#pragma unroll
      for (int r = 0; r < 4; ++r) {
        float pv = __expf(S[j][r] * 0.125f);
        lacc[r] += pv;
        Pw[(quad * 4 + r) * 72 + 16 * j + l15] = f2bf(pv);
      }
    __syncthreads();
#pragma unroll
    for (int c = 0; c < 2; ++c) {
      u16x8 pa = *(const u16x8*)(Pw + l15 * 72 + c * 32 + quad * 8);
#pragma unroll
      for (int dt = 0; dt < 4; ++dt) {
        u16x8 vf = *(const u16x8*)(Vl + (16 * dt + l15) * 72 + c * 32 + quad * 8);
        O[dt] = mfma16(pa, vf, O[dt]);
      }
    }
    __syncthreads();
  }
#pragma unroll
  for (int r = 0; r < 4; ++r) {
#pragma unroll
    for (int off = 1; off < 16; off <<= 1) lacc[r] += __shfl_xor(lacc[r], off);
  }
  const int b = bh >> 4, h = bh & 15;
#pragma unroll
  for (int r = 0; r < 4; ++r) {
    const float inv = 1.f / lacc[r];
    u16* orow = xo + (size_t)(b * 1024 + qrow0 + quad * 4 + r) * 1024 + h * 64;
#pragma unroll
    for (int dt = 0; dt < 4; ++dt) orow[16 * dt + l15] = f2bf(O[dt][r] * inv);
  }
}

extern "C" void kernel_launch(void* const* d_in, const int* in_sizes, int n_in,
                              void* d_out, int out_size, void* d_ws, size_t ws_size,
                              hipStream_t stream) {
  (void)in_sizes; (void)n_in; (void)out_size; (void)ws_size;
  const float* x      = (const float*)d_in[0];
  const float* norm_g = (const float*)d_in[1];
  const float* norm_b = (const float*)d_in[2];
  const float* W1     = (const float*)d_in[3];
  const float* b1     = (const float*)d_in[4];
  const float* qn_g   = (const float*)d_in[5];
  const float* qn_b   = (const float*)d_in[6];
  const float* kn_g   = (const float*)d_in[7];
  const float* kn_b   = (const float*)d_in[8];
  const float* projW  = (const float*)d_in[9];
  const float* projb  = (const float*)d_in[10];
  const float* mlpW   = (const float*)d_in[11];
  const float* W2     = (const float*)d_in[12];
  const float* b2     = (const float*)d_in[13];
  const float* ls_g   = (const float*)d_in[14];

  char* ws = (char*)d_ws;
  u16* W1t  = (u16*)(ws + 0);          // [3840][1024]  7,864,320
  u16* pWt  = (u16*)(ws + 7864320);    // [1024][1024]  2,097,152
  u16* mWt  = (u16*)(ws + 9961472);    // [1024][768]   1,572,864
  u16* W2t  = (u16*)(ws + 11534336);   // [1024][2048]  4,194,304
  u16* nx   = (u16*)(ws + 15728640);   // [4096][1024]  8,388,608 (then xo)
  u16* f1   = (u16*)(ws + 24117248);   // [4096][3840] 31,457,280 (then comb [4096][2048])
  u16* qbuf = (u16*)(ws + 55574528);   // [64][1024][64] 8,388,608
  u16* kbuf = (u16*)(ws + 63963136);   // [64][1024][64] 8,388,608
  u16* vtb  = (u16*)(ws + 72351744);   // [64][64][1024] 8,388,608
  u16* gel  = (u16*)(ws + 80740352);   // [4096][768]   6,291,456

  k_trcvt_all<<<7680, 256, 0, stream>>>(W1, projW, mlpW, W2, W1t, pWt, mWt, W2t);
  k_lnx<<<4096, 256, 0, stream>>>(x, norm_g, norm_b, nx);
  k_gemm<0><<<dim3(30, 32), 256, 0, stream>>>(nx, W1t, 1024, f1, 3840, b1, 3788,
                                              nullptr, nullptr);
  k_qkvgelu<<<5632, 256, 0, stream>>>(f1, qn_g, qn_b, kn_g, kn_b, qbuf, kbuf, gel);
  k_trvt<<<dim3(2, 32, 64), 256, 0, stream>>>(f1, vtb);
  k_flash<<<1024, 256, 0, stream>>>(qbuf, kbuf, vtb, nx);
  k_gemm64_pm<<<dim3(32, 32), 256, 0, stream>>>(nx, pWt, gel, mWt, f1, projb);
  k_gemm64f<<<dim3(16, 32), 256, 0, stream>>>(f1, W2t, (float*)d_out, b2, x, ls_g);
}

// Round 6
// 248.576 us; speedup vs baseline: 1.6455x; 1.1598x over previous
//
#include <hip/hip_runtime.h>
#include <cstdint>
#include <cstddef>

typedef unsigned short u16;
typedef unsigned char u8;
typedef __attribute__((ext_vector_type(8))) u16 u16x8;
typedef __attribute__((ext_vector_type(8))) __bf16 bf16x8;
typedef __attribute__((ext_vector_type(4))) float f32x4;
typedef __attribute__((ext_vector_type(16))) float f32x16;
typedef __attribute__((ext_vector_type(4))) int i32x4;
typedef __attribute__((ext_vector_type(8))) int i32x8;

__device__ __forceinline__ u16 f2bf(float f) {
  unsigned u = __builtin_bit_cast(unsigned, f);
  return (u16)((u + 0x7FFFu + ((u >> 16) & 1u)) >> 16);
}
__device__ __forceinline__ float bf2f(u16 h) {
  return __builtin_bit_cast(float, (unsigned)h << 16);
}
__device__ __forceinline__ u8 f2fp8(float f) {
  return (u8)(__builtin_amdgcn_cvt_pk_fp8_f32(f, 0.f, 0, false) & 0xFF);
}
__device__ __forceinline__ f32x4 mfma16(u16x8 a, u16x8 b, f32x4 c) {
  return __builtin_amdgcn_mfma_f32_16x16x32_bf16(
      __builtin_bit_cast(bf16x8, a), __builtin_bit_cast(bf16x8, b), c, 0, 0, 0);
}
__device__ __forceinline__ void load_lds16(const void* g, void* l) {
  __builtin_amdgcn_global_load_lds(
      (const __attribute__((address_space(1))) void*)g,
      (__attribute__((address_space(3))) void*)l, 16, 0, 0);
}

// ---------------- all 4 weight transposes fused: dst[n][k] = fp8(src[k][n]), zero-padded
__global__ __launch_bounds__(256) void k_trcvt_all(
    const float* __restrict__ W1, const float* __restrict__ projW,
    const float* __restrict__ mlpW, const float* __restrict__ W2,
    u8* __restrict__ W1t, u8* __restrict__ pWt, u8* __restrict__ mWt,
    u8* __restrict__ W2t) {
  __shared__ float t[32][33];
  const int L = blockIdx.x;
  const float* src;
  u8* dst;
  int R, C, dR, dC, bx, by;
  if (L < 3840) {
    src = W1; dst = W1t; R = 1024; C = 3788; dR = 1024; dC = 3840;
    bx = L % 120; by = L / 120;
  } else if (L < 4864) {
    int tq = L - 3840;
    src = projW; dst = pWt; R = 1024; C = 1024; dR = 1024; dC = 1024;
    bx = tq & 31; by = tq >> 5;
  } else if (L < 5632) {
    int tq = L - 4864;
    src = mlpW; dst = mWt; R = 716; C = 1024; dR = 768; dC = 1024;
    bx = tq & 31; by = tq >> 5;
  } else {
    int tq = L - 5632;
    src = W2; dst = W2t; R = 2048; C = 1024; dR = 2048; dC = 1024;
    bx = tq & 31; by = tq >> 5;
  }
  const int n0 = bx * 32, k0 = by * 32;
  const int tx = threadIdx.x & 31, ty = threadIdx.x >> 5;
#pragma unroll
  for (int j = 0; j < 4; ++j) {
    int kk = k0 + ty + 8 * j, nn = n0 + tx;
    float v = (kk < R && nn < C) ? src[(size_t)kk * C + nn] : 0.f;
    t[ty + 8 * j][tx] = v;
  }
  __syncthreads();
#pragma unroll
  for (int j = 0; j < 4; ++j) {
    int nn = n0 + ty + 8 * j, kk = k0 + tx;
    if (nn < dC && kk < dR) dst[(size_t)nn * dR + kk] = f2fp8(t[tx][ty + 8 * j]);
  }
}

// ---------------- V^T extraction from f1 (bf16): vtb[bh][d][n]
__global__ __launch_bounds__(256) void k_trvt(const u16* __restrict__ f1,
                                              u16* __restrict__ vtb) {
  __shared__ u16 t[32][33];
  const int z = blockIdx.z;
  const int b = z >> 4, h = z & 15;
  const int d0 = blockIdx.x * 32, n0 = blockIdx.y * 32;
  const int tx = threadIdx.x & 31, ty = threadIdx.x >> 5;
#pragma unroll
  for (int j = 0; j < 4; ++j)
    t[ty + 8 * j][tx] =
        f1[(size_t)(b * 1024 + n0 + ty + 8 * j) * 3840 + 2048 + h * 64 + d0 + tx];
  __syncthreads();
#pragma unroll
  for (int j = 0; j < 4; ++j)
    vtb[(size_t)z * 65536 + (size_t)(d0 + ty + 8 * j) * 1024 + n0 + tx] =
        t[tx][ty + 8 * j];
}

// ---------------- LayerNorm over DIM=1024, fp32 in -> fp8 out
__global__ __launch_bounds__(256) void k_lnx(const float* __restrict__ x,
                                             const float* __restrict__ g,
                                             const float* __restrict__ b,
                                             u8* __restrict__ out) {
  const int row = blockIdx.x, tid = threadIdx.x;
  float4 v = ((const float4*)(x + (size_t)row * 1024))[tid];
  float s = v.x + v.y + v.z + v.w;
  float ss = v.x * v.x + v.y * v.y + v.z * v.z + v.w * v.w;
#pragma unroll
  for (int off = 1; off < 64; off <<= 1) {
    s += __shfl_xor(s, off);
    ss += __shfl_xor(ss, off);
  }
  __shared__ float red[8];
  const int wid = tid >> 6, lane = tid & 63;
  if (lane == 0) { red[wid] = s; red[4 + wid] = ss; }
  __syncthreads();
  s = red[0] + red[1] + red[2] + red[3];
  ss = red[4] + red[5] + red[6] + red[7];
  const float mean = s * (1.f / 1024.f);
  const float var = ss * (1.f / 1024.f) - mean * mean;
  const float rstd = rsqrtf(var + 1e-5f);
  float4 gv = ((const float4*)g)[tid];
  float4 bv = ((const float4*)b)[tid];
  float y0 = (v.x - mean) * rstd * gv.x + bv.x;
  float y1 = (v.y - mean) * rstd * gv.y + bv.y;
  float y2 = (v.z - mean) * rstd * gv.z + bv.z;
  float y3 = (v.w - mean) * rstd * gv.w + bv.w;
  int pk = __builtin_amdgcn_cvt_pk_fp8_f32(y0, y1, 0, false);
  pk = __builtin_amdgcn_cvt_pk_fp8_f32(y2, y3, pk, true);
  ((int*)(out + (size_t)row * 1024))[tid] = pk;
}

// ---------------- MX-fp8 GEMM core: 128x128 tile, 32x32x64 f8f6f4, unit scales.
// LDS rows 64B; chunk c of row r stored at pos = c ^ ((r>>1)&3) (16B chunks).
// Staging dest = base + slot*16 (wave-uniform + lane*16, m104-compliant).
__device__ __forceinline__ void gemm_fp8_core(const u8* __restrict__ A,
                                              const u8* __restrict__ B, int K,
                                              u8* Alds, u8* Blds,
                                              f32x16 (&acc)[2][2], int tid) {
  const int lane = tid & 63, wave = tid >> 6;
  const int h = lane >> 5, r32 = lane & 31;
  const int wrow = (wave >> 1) * 64, wcol = (wave & 1) * 64;
  const int srow0 = tid >> 2, spos = tid & 3;
  const int nk = K >> 6;
  for (int kt = 0; kt < nk; ++kt) {
#pragma unroll
    for (int p = 0; p < 2; ++p) {
      const int row = p * 64 + srow0;
      const int c = spos ^ ((row >> 1) & 3);
      const size_t go = (size_t)row * K + kt * 64 + c * 16;
      load_lds16(A + go, Alds + (p * 256 + tid) * 16);
      load_lds16(B + go, Blds + (p * 256 + tid) * 16);
    }
    __syncthreads();
    i32x8 af[2], bf[2];
#pragma unroll
    for (int t = 0; t < 2; ++t) {
      {
        const int row = wrow + t * 32 + r32;
        const int sw = (row >> 1) & 3;
        i32x4 lo = *(const i32x4*)(Alds + row * 64 + ((2 * h) ^ sw) * 16);
        i32x4 hi = *(const i32x4*)(Alds + row * 64 + ((2 * h + 1) ^ sw) * 16);
        i32x8 a;
        a[0] = lo[0]; a[1] = lo[1]; a[2] = lo[2]; a[3] = lo[3];
        a[4] = hi[0]; a[5] = hi[1]; a[6] = hi[2]; a[7] = hi[3];
        af[t] = a;
      }
      {
        const int row = wcol + t * 32 + r32;
        const int sw = (row >> 1) & 3;
        i32x4 lo = *(const i32x4*)(Blds + row * 64 + ((2 * h) ^ sw) * 16);
        i32x4 hi = *(const i32x4*)(Blds + row * 64 + ((2 * h + 1) ^ sw) * 16);
        i32x8 b8;
        b8[0] = lo[0]; b8[1] = lo[1]; b8[2] = lo[2]; b8[3] = lo[3];
        b8[4] = hi[0]; b8[5] = hi[1]; b8[6] = hi[2]; b8[7] = hi[3];
        bf[t] = b8;
      }
    }
#pragma unroll
    for (int i = 0; i < 2; ++i)
#pragma unroll
      for (int j = 0; j < 2; ++j)
        acc[i][j] = __builtin_amdgcn_mfma_scale_f32_32x32x64_f8f6f4(
            af[i], bf[j], acc[i][j], 0, 0, 0, 0x7F7F7F7F, 0, 0x7F7F7F7F);
    __syncthreads();
  }
}

// ---------------- GEMM1: f1[4096][3840] bf16 = nx8 @ W1t^T + b1
__global__ __launch_bounds__(256) void k_gemm1(const u8* __restrict__ nx8,
                                               const u8* __restrict__ W1t,
                                               u16* __restrict__ f1,
                                               const float* __restrict__ b1) {
  __shared__ __align__(16) u8 Alds[128 * 64];
  __shared__ __align__(16) u8 Blds[128 * 64];
  const int tid = threadIdx.x, bm = blockIdx.y, bn = blockIdx.x;
  f32x16 acc[2][2];
#pragma unroll
  for (int i = 0; i < 2; ++i)
#pragma unroll
    for (int j = 0; j < 2; ++j)
#pragma unroll
      for (int r = 0; r < 16; ++r) acc[i][j][r] = 0.f;
  gemm_fp8_core(nx8 + (size_t)bm * 128 * 1024, W1t + (size_t)bn * 128 * 1024, 1024,
                Alds, Blds, acc, tid);
  const int lane = tid & 63, wave = tid >> 6;
  const int h = lane >> 5, r32 = lane & 31;
  const int wrow = (wave >> 1) * 64, wcol = (wave & 1) * 64;
#pragma unroll
  for (int i = 0; i < 2; ++i)
#pragma unroll
    for (int j = 0; j < 2; ++j) {
      const int col = bn * 128 + wcol + j * 32 + r32;
      const float bs = (col < 3788) ? b1[col] : 0.f;
#pragma unroll
      for (int r = 0; r < 16; ++r) {
        const int row = bm * 128 + wrow + i * 32 + 4 * h + (r & 3) + 8 * (r >> 2);
        f1[(size_t)row * 3840 + col] = f2bf(acc[i][j][r] + bs);
      }
    }
}

// ---------------- proj + mlp fused: comb[4096][2048] fp8
__global__ __launch_bounds__(256) void k_gemm_pm(
    const u8* __restrict__ xo, const u8* __restrict__ pWt,
    const u8* __restrict__ gel, const u8* __restrict__ mWt,
    u8* __restrict__ comb, const float* __restrict__ projb) {
  __shared__ __align__(16) u8 Alds[128 * 64];
  __shared__ __align__(16) u8 Blds[128 * 64];
  const int tid = threadIdx.x, bm = blockIdx.y, bnq = blockIdx.x;
  const u8* A;
  const u8* B;
  int K, colbase;
  const float* bias;
  if (bnq < 8) {
    A = xo + (size_t)bm * 128 * 1024;
    B = pWt + (size_t)bnq * 128 * 1024;
    K = 1024; colbase = bnq * 128; bias = projb;
  } else {
    A = gel + (size_t)bm * 128 * 768;
    B = mWt + (size_t)(bnq - 8) * 128 * 768;
    K = 768; colbase = 1024 + (bnq - 8) * 128; bias = nullptr;
  }
  f32x16 acc[2][2];
#pragma unroll
  for (int i = 0; i < 2; ++i)
#pragma unroll
    for (int j = 0; j < 2; ++j)
#pragma unroll
      for (int r = 0; r < 16; ++r) acc[i][j][r] = 0.f;
  gemm_fp8_core(A, B, K, Alds, Blds, acc, tid);
  const int lane = tid & 63, wave = tid >> 6;
  const int h = lane >> 5, r32 = lane & 31;
  const int wrow = (wave >> 1) * 64, wcol = (wave & 1) * 64;
#pragma unroll
  for (int i = 0; i < 2; ++i)
#pragma unroll
    for (int j = 0; j < 2; ++j) {
      const int col = colbase + wcol + j * 32 + r32;
      const float bs = (bias != nullptr) ? bias[col - colbase + colbase -
                                               (bias == projb ? 0 : 0)] : 0.f;
      const float bsv = (bias != nullptr) ? bias[wcol + j * 32 + r32 + 0 +
                                                 (colbase - colbase)] : 0.f;
      (void)bs;
#pragma unroll
      for (int r = 0; r < 16; ++r) {
        const int row = bm * 128 + wrow + i * 32 + 4 * h + (r & 3) + 8 * (r >> 2);
        float v = acc[i][j][r] + ((bias != nullptr) ? bias[col] : 0.f);
        (void)bsv;
        comb[(size_t)row * 2048 + col] = f2fp8(v);
      }
    }
}

// ---------------- final: out = x + (comb @ W2t^T + b2) * ls_g  (fp32)
__global__ __launch_bounds__(256) void k_gemm_fin(const u8* __restrict__ comb,
                                                  const u8* __restrict__ W2t,
                                                  float* __restrict__ out,
                                                  const float* __restrict__ b2,
                                                  const float* __restrict__ x,
                                                  const float* __restrict__ lsg) {
  __shared__ __align__(16) u8 Alds[128 * 64];
  __shared__ __align__(16) u8 Blds[128 * 64];
  const int tid = threadIdx.x, bm = blockIdx.y, bn = blockIdx.x;
  f32x16 acc[2][2];
#pragma unroll
  for (int i = 0; i < 2; ++i)
#pragma unroll
    for (int j = 0; j < 2; ++j)
#pragma unroll
      for (int r = 0; r < 16; ++r) acc[i][j][r] = 0.f;
  gemm_fp8_core(comb + (size_t)bm * 128 * 2048, W2t + (size_t)bn * 128 * 2048, 2048,
                Alds, Blds, acc, tid);
  const int lane = tid & 63, wave = tid >> 6;
  const int h = lane >> 5, r32 = lane & 31;
  const int wrow = (wave >> 1) * 64, wcol = (wave & 1) * 64;
#pragma unroll
  for (int i = 0; i < 2; ++i)
#pragma unroll
    for (int j = 0; j < 2; ++j) {
      const int col = bn * 128 + wcol + j * 32 + r32;
      const float bs = b2[col], ls = lsg[col];
#pragma unroll
      for (int r = 0; r < 16; ++r) {
        const int row = bm * 128 + wrow + i * 32 + 4 * h + (r & 3) + 8 * (r >> 2);
        out[(size_t)row * 1024 + col] =
            x[(size_t)row * 1024 + col] + (acc[i][j][r] + bs) * ls;
      }
    }
}

// ---------------- q/k per-head LN (bf16 out) + gelu (fp8 out), one launch
__global__ __launch_bounds__(256) void k_qkvgelu(const u16* __restrict__ f1,
                                                 const float* __restrict__ qg,
                                                 const float* __restrict__ qbb,
                                                 const float* __restrict__ kg,
                                                 const float* __restrict__ kbb,
                                                 u16* __restrict__ q,
                                                 u16* __restrict__ k,
                                                 u8* __restrict__ gel) {
  const int tid = threadIdx.x;
  if (blockIdx.x < 4096) {
    const int row = blockIdx.x;
    const int rem = tid >> 3;
    const int which = rem >> 4, h = rem & 15;
    const int e8 = (tid & 7) * 8;
    u16x8 xv = *(const u16x8*)(f1 + (size_t)row * 3840 + which * 1024 + h * 64 + e8);
    float xf[8];
    float s1 = 0.f, s2 = 0.f;
#pragma unroll
    for (int e = 0; e < 8; ++e) {
      xf[e] = bf2f(xv[e]);
      s1 += xf[e];
      s2 += xf[e] * xf[e];
    }
#pragma unroll
    for (int off = 1; off < 8; off <<= 1) {
      s1 += __shfl_xor(s1, off);
      s2 += __shfl_xor(s2, off);
    }
    const float mean = s1 * (1.f / 64.f);
    const float var = s2 * (1.f / 64.f) - mean * mean;
    const float rstd = rsqrtf(var + 1e-5f);
    const float* g = (which == 0) ? qg : kg;
    const float* bb = (which == 0) ? qbb : kbb;
    float4 g0 = ((const float4*)g)[e8 >> 2], g1 = ((const float4*)g)[(e8 >> 2) + 1];
    float4 b0 = ((const float4*)bb)[e8 >> 2], b1 = ((const float4*)bb)[(e8 >> 2) + 1];
    float gv[8] = {g0.x, g0.y, g0.z, g0.w, g1.x, g1.y, g1.z, g1.w};
    float bv[8] = {b0.x, b0.y, b0.z, b0.w, b1.x, b1.y, b1.z, b1.w};
    u16x8 o;
#pragma unroll
    for (int e = 0; e < 8; ++e) o[e] = f2bf((xf[e] - mean) * rstd * gv[e] + bv[e]);
    const int b = row >> 10, n = row & 1023;
    u16* dst = (which == 0) ? q : k;
    *(u16x8*)(dst + ((size_t)(b * 16 + h) * 1024 + n) * 64 + e8) = o;
  } else {
    const int id = (blockIdx.x - 4096) * 256 + tid;
    const int row = id / 96, c8 = id - row * 96;
    u16x8 xv = *(const u16x8*)(f1 + (size_t)row * 3840 + 3072 + c8 * 8);
    float rr[8];
#pragma unroll
    for (int e = 0; e < 8; ++e) {
      const int col = c8 * 8 + e;
      rr[e] = 0.f;
      if (col < 716) {
        float xx = bf2f(xv[e]);
        rr[e] = 0.5f * xx * (1.f + erff(xx * 0.70710678118654752f));
      }
    }
    int p0 = __builtin_amdgcn_cvt_pk_fp8_f32(rr[0], rr[1], 0, false);
    p0 = __builtin_amdgcn_cvt_pk_fp8_f32(rr[2], rr[3], p0, true);
    int p1 = __builtin_amdgcn_cvt_pk_fp8_f32(rr[4], rr[5], 0, false);
    p1 = __builtin_amdgcn_cvt_pk_fp8_f32(rr[6], rr[7], p1, true);
    uint2 pk;
    pk.x = (unsigned)p0;
    pk.y = (unsigned)p1;
    *(uint2*)(gel + (size_t)row * 768 + c8 * 8) = pk;
  }
}

// ---------------- flash attention (bf16), xo out fp8
__global__ __launch_bounds__(256) void k_flash(const u16* __restrict__ q,
                                               const u16* __restrict__ k,
                                               const u16* __restrict__ vt,
                                               u8* __restrict__ xo) {
  __shared__ __align__(16) u16 Kl[64 * 72];
  __shared__ __align__(16) u16 Vl[64 * 72];
  __shared__ __align__(16) u16 Pl[4 * 16 * 72];
  const int tid = threadIdx.x, wave = tid >> 6, lane = tid & 63;
  const int l15 = lane & 15, quad = lane >> 4;
  const int L = blockIdx.x;
  const int xcd = L & 7, idx = L >> 3;
  const int bh = xcd * 8 + (idx & 7), qt = idx >> 3;
  const int qrow0 = qt * 64 + wave * 16;
  const u16* qb = q + ((size_t)bh * 1024 + qrow0) * 64;
  const u16* kb = k + (size_t)bh * 1024 * 64;
  const u16* vb = vt + (size_t)bh * 64 * 1024;
  u16* Pw = Pl + wave * 16 * 72;

  u16x8 qf[2];
#pragma unroll
  for (int kk = 0; kk < 2; ++kk)
    qf[kk] = *(const u16x8*)(qb + (size_t)l15 * 64 + kk * 32 + quad * 8);

  f32x4 O[4];
  float lacc[4] = {0.f, 0.f, 0.f, 0.f};
#pragma unroll
  for (int dt = 0; dt < 4; ++dt) O[dt] = f32x4{0.f, 0.f, 0.f, 0.f};

  for (int kv = 0; kv < 16; ++kv) {
#pragma unroll
    for (int p = 0; p < 2; ++p) {
      const int ci = p * 256 + tid;
      const int r = ci >> 3, off = (ci & 7) * 8;
      *(u16x8*)(Kl + r * 72 + off) =
          *(const u16x8*)(kb + (size_t)(kv * 64 + r) * 64 + off);
      *(u16x8*)(Vl + r * 72 + off) =
          *(const u16x8*)(vb + (size_t)r * 1024 + kv * 64 + off);
    }
    __syncthreads();
    f32x4 S[4];
#pragma unroll
    for (int j = 0; j < 4; ++j) S[j] = f32x4{0.f, 0.f, 0.f, 0.f};
#pragma unroll
    for (int j = 0; j < 4; ++j)
#pragma unroll
      for (int kk = 0; kk < 2; ++kk) {
        u16x8 bfr = *(const u16x8*)(Kl + (16 * j + l15) * 72 + kk * 32 + quad * 8);
        S[j] = mfma16(qf[kk], bfr, S[j]);
      }
#pragma unroll
    for (int j = 0; j < 4; ++j)
#pragma unroll
      for (int r = 0; r < 4; ++r) {
        float pv = __expf(S[j][r] * 0.125f);
        lacc[r] += pv;
        Pw[(quad * 4 + r) * 72 + 16 * j + l15] = f2bf(pv);
      }
    __syncthreads();
#pragma unroll
    for (int c = 0; c < 2; ++c) {
      u16x8 pa = *(const u16x8*)(Pw + l15 * 72 + c * 32 + quad * 8);
#pragma unroll
      for (int dt = 0; dt < 4; ++dt) {
        u16x8 vf = *(const u16x8*)(Vl + (16 * dt + l15) * 72 + c * 32 + quad * 8);
        O[dt] = mfma16(pa, vf, O[dt]);
      }
    }
    __syncthreads();
  }
#pragma unroll
  for (int r = 0; r < 4; ++r) {
#pragma unroll
    for (int off = 1; off < 16; off <<= 1) lacc[r] += __shfl_xor(lacc[r], off);
  }
  const int b = bh >> 4, h = bh & 15;
#pragma unroll
  for (int r = 0; r < 4; ++r) {
    const float inv = 1.f / lacc[r];
    u8* orow = xo + (size_t)(b * 1024 + qrow0 + quad * 4 + r) * 1024 + h * 64;
#pragma unroll
    for (int dt = 0; dt < 4; ++dt) orow[16 * dt + l15] = f2fp8(O[dt][r] * inv);
  }
}

extern "C" void kernel_launch(void* const* d_in, const int* in_sizes, int n_in,
                              void* d_out, int out_size, void* d_ws, size_t ws_size,
                              hipStream_t stream) {
  (void)in_sizes; (void)n_in; (void)out_size; (void)ws_size;
  const float* x      = (const float*)d_in[0];
  const float* norm_g = (const float*)d_in[1];
  const float* norm_b = (const float*)d_in[2];
  const float* W1     = (const float*)d_in[3];
  const float* b1     = (const float*)d_in[4];
  const float* qn_g   = (const float*)d_in[5];
  const float* qn_b   = (const float*)d_in[6];
  const float* kn_g   = (const float*)d_in[7];
  const float* kn_b   = (const float*)d_in[8];
  const float* projW  = (const float*)d_in[9];
  const float* projb  = (const float*)d_in[10];
  const float* mlpW   = (const float*)d_in[11];
  const float* W2     = (const float*)d_in[12];
  const float* b2     = (const float*)d_in[13];
  const float* ls_g   = (const float*)d_in[14];

  char* ws = (char*)d_ws;
  u8*  W1t8 = (u8*)(ws + 0);           // [3840][1024]  3,932,160
  u8*  pWt8 = (u8*)(ws + 3932160);     // [1024][1024]  1,048,576
  u8*  mWt8 = (u8*)(ws + 4980736);     // [1024][768]     786,432
  u8*  W2t8 = (u8*)(ws + 5767168);     // [1024][2048]  2,097,152
  u8*  nx8  = (u8*)(ws + 7864320);     // [4096][1024]  4,194,304 (then xo8)
  u16* f1   = (u16*)(ws + 12058624);   // [4096][3840] 31,457,280 bf16 (then comb fp8 [4096][2048])
  u16* qbuf = (u16*)(ws + 43515904);   // [64][1024][64] 8,388,608
  u16* kbuf = (u16*)(ws + 51904512);   // [64][1024][64] 8,388,608
  u16* vtb  = (u16*)(ws + 60293120);   // [64][64][1024] 8,388,608
  u8*  gel8 = (u8*)(ws + 68681728);    // [4096][768]   3,145,728

  k_trcvt_all<<<7680, 256, 0, stream>>>(W1, projW, mlpW, W2, W1t8, pWt8, mWt8, W2t8);
  k_lnx<<<4096, 256, 0, stream>>>(x, norm_g, norm_b, nx8);
  k_gemm1<<<dim3(30, 32), 256, 0, stream>>>(nx8, W1t8, f1, b1);
  k_qkvgelu<<<5632, 256, 0, stream>>>(f1, qn_g, qn_b, kn_g, kn_b, qbuf, kbuf, gel8);
  k_trvt<<<dim3(2, 32, 64), 256, 0, stream>>>(f1, vtb);
  k_flash<<<1024, 256, 0, stream>>>(qbuf, kbuf, vtb, nx8);
  k_gemm_pm<<<dim3(16, 32), 256, 0, stream>>>(nx8, pWt8, gel8, mWt8, (u8*)f1, projb);
  k_gemm_fin<<<dim3(8, 32), 256, 0, stream>>>((u8*)f1, W2t8, (float*)d_out, b2, x,
                                              ls_g);
}

// Round 7
// 238.087 us; speedup vs baseline: 1.7180x; 1.0441x over previous
//
#include <hip/hip_runtime.h>
#include <cstdint>
#include <cstddef>

typedef unsigned short u16;
typedef unsigned char u8;
typedef __attribute__((ext_vector_type(8))) u16 u16x8;
typedef __attribute__((ext_vector_type(8))) __bf16 bf16x8;
typedef __attribute__((ext_vector_type(4))) float f32x4;
typedef __attribute__((ext_vector_type(16))) float f32x16;
typedef __attribute__((ext_vector_type(4))) int i32x4;
typedef __attribute__((ext_vector_type(8))) int i32x8;

__device__ __forceinline__ u16 f2bf(float f) {
  unsigned u = __builtin_bit_cast(unsigned, f);
  return (u16)((u + 0x7FFFu + ((u >> 16) & 1u)) >> 16);
}
__device__ __forceinline__ float bf2f(u16 h) {
  return __builtin_bit_cast(float, (unsigned)h << 16);
}
__device__ __forceinline__ u8 f2fp8(float f) {
  return (u8)(__builtin_amdgcn_cvt_pk_fp8_f32(f, 0.f, 0, false) & 0xFF);
}
__device__ __forceinline__ f32x4 mfma16(u16x8 a, u16x8 b, f32x4 c) {
  return __builtin_amdgcn_mfma_f32_16x16x32_bf16(
      __builtin_bit_cast(bf16x8, a), __builtin_bit_cast(bf16x8, b), c, 0, 0, 0);
}
__device__ __forceinline__ void load_lds16(const void* g, void* l) {
  __builtin_amdgcn_global_load_lds(
      (const __attribute__((address_space(1))) void*)g,
      (__attribute__((address_space(3))) void*)l, 16, 0, 0);
}

// ---------------- all 4 weight transposes fused: dst[n][k] = fp8(src[k][n]), zero-padded
__global__ __launch_bounds__(256) void k_trcvt_all(
    const float* __restrict__ W1, const float* __restrict__ projW,
    const float* __restrict__ mlpW, const float* __restrict__ W2,
    u8* __restrict__ W1t, u8* __restrict__ pWt, u8* __restrict__ mWt,
    u8* __restrict__ W2t) {
  __shared__ float t[32][33];
  const int L = blockIdx.x;
  const float* src;
  u8* dst;
  int R, C, dR, dC, bx, by;
  if (L < 3840) {
    src = W1; dst = W1t; R = 1024; C = 3788; dR = 1024; dC = 3840;
    bx = L % 120; by = L / 120;
  } else if (L < 4864) {
    int tq = L - 3840;
    src = projW; dst = pWt; R = 1024; C = 1024; dR = 1024; dC = 1024;
    bx = tq & 31; by = tq >> 5;
  } else if (L < 5632) {
    int tq = L - 4864;
    src = mlpW; dst = mWt; R = 716; C = 1024; dR = 768; dC = 1024;
    bx = tq & 31; by = tq >> 5;
  } else {
    int tq = L - 5632;
    src = W2; dst = W2t; R = 2048; C = 1024; dR = 2048; dC = 1024;
    bx = tq & 31; by = tq >> 5;
  }
  const int n0 = bx * 32, k0 = by * 32;
  const int tx = threadIdx.x & 31, ty = threadIdx.x >> 5;
#pragma unroll
  for (int j = 0; j < 4; ++j) {
    int kk = k0 + ty + 8 * j, nn = n0 + tx;
    float v = (kk < R && nn < C) ? src[(size_t)kk * C + nn] : 0.f;
    t[ty + 8 * j][tx] = v;
  }
  __syncthreads();
#pragma unroll
  for (int j = 0; j < 4; ++j) {
    int nn = n0 + ty + 8 * j, kk = k0 + tx;
    if (nn < dC && kk < dR) dst[(size_t)nn * dR + kk] = f2fp8(t[tx][ty + 8 * j]);
  }
}

// ---------------- V^T extraction from f1 (bf16): vtb[bh][d][n]
__global__ __launch_bounds__(256) void k_trvt(const u16* __restrict__ f1,
                                              u16* __restrict__ vtb) {
  __shared__ u16 t[32][33];
  const int z = blockIdx.z;
  const int b = z >> 4, h = z & 15;
  const int d0 = blockIdx.x * 32, n0 = blockIdx.y * 32;
  const int tx = threadIdx.x & 31, ty = threadIdx.x >> 5;
#pragma unroll
  for (int j = 0; j < 4; ++j)
    t[ty + 8 * j][tx] =
        f1[(size_t)(b * 1024 + n0 + ty + 8 * j) * 3840 + 2048 + h * 64 + d0 + tx];
  __syncthreads();
#pragma unroll
  for (int j = 0; j < 4; ++j)
    vtb[(size_t)z * 65536 + (size_t)(d0 + ty + 8 * j) * 1024 + n0 + tx] =
        t[tx][ty + 8 * j];
}

// ---------------- LayerNorm over DIM=1024, fp32 in -> fp8 out
__global__ __launch_bounds__(256) void k_lnx(const float* __restrict__ x,
                                             const float* __restrict__ g,
                                             const float* __restrict__ b,
                                             u8* __restrict__ out) {
  const int row = blockIdx.x, tid = threadIdx.x;
  float4 v = ((const float4*)(x + (size_t)row * 1024))[tid];
  float s = v.x + v.y + v.z + v.w;
  float ss = v.x * v.x + v.y * v.y + v.z * v.z + v.w * v.w;
#pragma unroll
  for (int off = 1; off < 64; off <<= 1) {
    s += __shfl_xor(s, off);
    ss += __shfl_xor(ss, off);
  }
  __shared__ float red[8];
  const int wid = tid >> 6, lane = tid & 63;
  if (lane == 0) { red[wid] = s; red[4 + wid] = ss; }
  __syncthreads();
  s = red[0] + red[1] + red[2] + red[3];
  ss = red[4] + red[5] + red[6] + red[7];
  const float mean = s * (1.f / 1024.f);
  const float var = ss * (1.f / 1024.f) - mean * mean;
  const float rstd = rsqrtf(var + 1e-5f);
  float4 gv = ((const float4*)g)[tid];
  float4 bv = ((const float4*)b)[tid];
  float y0 = (v.x - mean) * rstd * gv.x + bv.x;
  float y1 = (v.y - mean) * rstd * gv.y + bv.y;
  float y2 = (v.z - mean) * rstd * gv.z + bv.z;
  float y3 = (v.w - mean) * rstd * gv.w + bv.w;
  int pk = __builtin_amdgcn_cvt_pk_fp8_f32(y0, y1, 0, false);
  pk = __builtin_amdgcn_cvt_pk_fp8_f32(y2, y3, pk, true);
  ((int*)(out + (size_t)row * 1024))[tid] = pk;
}

// ---------------- MX-fp8 GEMM core 128x128 (GEMM1): 32x32x64 f8f6f4, unit scales.
__device__ __forceinline__ void gemm_fp8_core(const u8* __restrict__ A,
                                              const u8* __restrict__ B, int K,
                                              u8* Alds, u8* Blds,
                                              f32x16 (&acc)[2][2], int tid) {
  const int lane = tid & 63, wave = tid >> 6;
  const int h = lane >> 5, r32 = lane & 31;
  const int wrow = (wave >> 1) * 64, wcol = (wave & 1) * 64;
  const int srow0 = tid >> 2, spos = tid & 3;
  const int nk = K >> 6;
  for (int kt = 0; kt < nk; ++kt) {
#pragma unroll
    for (int p = 0; p < 2; ++p) {
      const int row = p * 64 + srow0;
      const int c = spos ^ ((row >> 1) & 3);
      const size_t go = (size_t)row * K + kt * 64 + c * 16;
      load_lds16(A + go, Alds + (p * 256 + tid) * 16);
      load_lds16(B + go, Blds + (p * 256 + tid) * 16);
    }
    __syncthreads();
    i32x8 af[2], bf[2];
#pragma unroll
    for (int t = 0; t < 2; ++t) {
      {
        const int row = wrow + t * 32 + r32;
        const int sw = (row >> 1) & 3;
        i32x4 lo = *(const i32x4*)(Alds + row * 64 + ((2 * h) ^ sw) * 16);
        i32x4 hi = *(const i32x4*)(Alds + row * 64 + ((2 * h + 1) ^ sw) * 16);
        i32x8 a;
        a[0] = lo[0]; a[1] = lo[1]; a[2] = lo[2]; a[3] = lo[3];
        a[4] = hi[0]; a[5] = hi[1]; a[6] = hi[2]; a[7] = hi[3];
        af[t] = a;
      }
      {
        const int row = wcol + t * 32 + r32;
        const int sw = (row >> 1) & 3;
        i32x4 lo = *(const i32x4*)(Blds + row * 64 + ((2 * h) ^ sw) * 16);
        i32x4 hi = *(const i32x4*)(Blds + row * 64 + ((2 * h + 1) ^ sw) * 16);
        i32x8 b8;
        b8[0] = lo[0]; b8[1] = lo[1]; b8[2] = lo[2]; b8[3] = lo[3];
        b8[4] = hi[0]; b8[5] = hi[1]; b8[6] = hi[2]; b8[7] = hi[3];
        bf[t] = b8;
      }
    }
#pragma unroll
    for (int i = 0; i < 2; ++i)
#pragma unroll
      for (int j = 0; j < 2; ++j)
        acc[i][j] = __builtin_amdgcn_mfma_scale_f32_32x32x64_f8f6f4(
            af[i], bf[j], acc[i][j], 0, 0, 0, 0x7F7F7F7F, 0, 0x7F7F7F7F);
    __syncthreads();
  }
}

// ---------------- MX-fp8 GEMM core 64(M)x128(N): more blocks/CU for small GEMMs
__device__ __forceinline__ void gemm_fp8_core64(const u8* __restrict__ A,
                                                const u8* __restrict__ B, int K,
                                                u8* Alds, u8* Blds,
                                                f32x16 (&acc)[2], int tid) {
  const int lane = tid & 63, wave = tid >> 6;
  const int h = lane >> 5, r32 = lane & 31;
  const int wrow = (wave >> 1) * 32, wcol = (wave & 1) * 64;
  const int nk = K >> 6;
  for (int kt = 0; kt < nk; ++kt) {
    {
      const int r = tid >> 2, pos = tid & 3;
      const int c = pos ^ ((r >> 1) & 3);
      load_lds16(A + (size_t)r * K + kt * 64 + c * 16, Alds + tid * 16);
    }
#pragma unroll
    for (int p = 0; p < 2; ++p) {
      const int s = tid + 256 * p;
      const int r = s >> 2, pos = s & 3;
      const int c = pos ^ ((r >> 1) & 3);
      load_lds16(B + (size_t)r * K + kt * 64 + c * 16, Blds + s * 16);
    }
    __syncthreads();
    i32x8 af, bf[2];
    {
      const int row = wrow + r32;
      const int sw = (row >> 1) & 3;
      i32x4 lo = *(const i32x4*)(Alds + row * 64 + ((2 * h) ^ sw) * 16);
      i32x4 hi = *(const i32x4*)(Alds + row * 64 + ((2 * h + 1) ^ sw) * 16);
      af[0] = lo[0]; af[1] = lo[1]; af[2] = lo[2]; af[3] = lo[3];
      af[4] = hi[0]; af[5] = hi[1]; af[6] = hi[2]; af[7] = hi[3];
    }
#pragma unroll
    for (int t = 0; t < 2; ++t) {
      const int row = wcol + t * 32 + r32;
      const int sw = (row >> 1) & 3;
      i32x4 lo = *(const i32x4*)(Blds + row * 64 + ((2 * h) ^ sw) * 16);
      i32x4 hi = *(const i32x4*)(Blds + row * 64 + ((2 * h + 1) ^ sw) * 16);
      i32x8 b8;
      b8[0] = lo[0]; b8[1] = lo[1]; b8[2] = lo[2]; b8[3] = lo[3];
      b8[4] = hi[0]; b8[5] = hi[1]; b8[6] = hi[2]; b8[7] = hi[3];
      bf[t] = b8;
    }
#pragma unroll
    for (int j = 0; j < 2; ++j)
      acc[j] = __builtin_amdgcn_mfma_scale_f32_32x32x64_f8f6f4(
          af, bf[j], acc[j], 0, 0, 0, 0x7F7F7F7F, 0, 0x7F7F7F7F);
    __syncthreads();
  }
}

// ---------------- GEMM1: f1[4096][3840] bf16 = nx8 @ W1t^T + b1
__global__ __launch_bounds__(256) void k_gemm1(const u8* __restrict__ nx8,
                                               const u8* __restrict__ W1t,
                                               u16* __restrict__ f1,
                                               const float* __restrict__ b1) {
  __shared__ __align__(16) u8 Alds[128 * 64];
  __shared__ __align__(16) u8 Blds[128 * 64];
  const int tid = threadIdx.x, bm = blockIdx.y, bn = blockIdx.x;
  f32x16 acc[2][2];
#pragma unroll
  for (int i = 0; i < 2; ++i)
#pragma unroll
    for (int j = 0; j < 2; ++j)
#pragma unroll
      for (int r = 0; r < 16; ++r) acc[i][j][r] = 0.f;
  gemm_fp8_core(nx8 + (size_t)bm * 128 * 1024, W1t + (size_t)bn * 128 * 1024, 1024,
                Alds, Blds, acc, tid);
  const int lane = tid & 63, wave = tid >> 6;
  const int h = lane >> 5, r32 = lane & 31;
  const int wrow = (wave >> 1) * 64, wcol = (wave & 1) * 64;
#pragma unroll
  for (int i = 0; i < 2; ++i)
#pragma unroll
    for (int j = 0; j < 2; ++j) {
      const int col = bn * 128 + wcol + j * 32 + r32;
      const float bs = (col < 3788) ? b1[col] : 0.f;
#pragma unroll
      for (int r = 0; r < 16; ++r) {
        const int row = bm * 128 + wrow + i * 32 + 4 * h + (r & 3) + 8 * (r >> 2);
        f1[(size_t)row * 3840 + col] = f2bf(acc[i][j][r] + bs);
      }
    }
}

// ---------------- proj + mlp fused (64-row tiles): comb[4096][2048] fp8
__global__ __launch_bounds__(256) void k_gemm_pm(
    const u8* __restrict__ xo, const u8* __restrict__ pWt,
    const u8* __restrict__ gel, const u8* __restrict__ mWt,
    u8* __restrict__ comb, const float* __restrict__ projb) {
  __shared__ __align__(16) u8 Alds[64 * 64];
  __shared__ __align__(16) u8 Blds[128 * 64];
  const int tid = threadIdx.x, bm = blockIdx.y, bnq = blockIdx.x;
  const u8* A;
  const u8* B;
  int K, colbase;
  const float* bias;
  if (bnq < 8) {
    A = xo + (size_t)bm * 64 * 1024;
    B = pWt + (size_t)bnq * 128 * 1024;
    K = 1024; colbase = bnq * 128; bias = projb;
  } else {
    A = gel + (size_t)bm * 64 * 768;
    B = mWt + (size_t)(bnq - 8) * 128 * 768;
    K = 768; colbase = 1024 + (bnq - 8) * 128; bias = nullptr;
  }
  f32x16 acc[2];
#pragma unroll
  for (int j = 0; j < 2; ++j)
#pragma unroll
    for (int r = 0; r < 16; ++r) acc[j][r] = 0.f;
  gemm_fp8_core64(A, B, K, Alds, Blds, acc, tid);
  const int lane = tid & 63, wave = tid >> 6;
  const int h = lane >> 5, r32 = lane & 31;
  const int wrow = (wave >> 1) * 32, wcol = (wave & 1) * 64;
#pragma unroll
  for (int j = 0; j < 2; ++j) {
    const int col = colbase + wcol + j * 32 + r32;
    const float bs = (bias != nullptr) ? bias[col - colbase + colbase - colbase +
                                              (bnq < 8 ? bnq * 128 : 0) - 
                                              (bnq < 8 ? bnq * 128 : 0) + 
                                              (wcol + j * 32 + r32)] : 0.f;
#pragma unroll
    for (int r = 0; r < 16; ++r) {
      const int row = bm * 64 + wrow + 4 * h + (r & 3) + 8 * (r >> 2);
      comb[(size_t)row * 2048 + col] = f2fp8(acc[j][r] + bs);
    }
  }
}

// ---------------- final (64-row tiles): out = x + (comb @ W2t^T + b2) * ls_g
__global__ __launch_bounds__(256) void k_gemm_fin(const u8* __restrict__ comb,
                                                  const u8* __restrict__ W2t,
                                                  float* __restrict__ out,
                                                  const float* __restrict__ b2,
                                                  const float* __restrict__ x,
                                                  const float* __restrict__ lsg) {
  __shared__ __align__(16) u8 Alds[64 * 64];
  __shared__ __align__(16) u8 Blds[128 * 64];
  const int tid = threadIdx.x, bm = blockIdx.y, bn = blockIdx.x;
  f32x16 acc[2];
#pragma unroll
  for (int j = 0; j < 2; ++j)
#pragma unroll
    for (int r = 0; r < 16; ++r) acc[j][r] = 0.f;
  gemm_fp8_core64(comb + (size_t)bm * 64 * 2048, W2t + (size_t)bn * 128 * 2048, 2048,
                  Alds, Blds, acc, tid);
  const int lane = tid & 63, wave = tid >> 6;
  const int h = lane >> 5, r32 = lane & 31;
  const int wrow = (wave >> 1) * 32, wcol = (wave & 1) * 64;
#pragma unroll
  for (int j = 0; j < 2; ++j) {
    const int col = bn * 128 + wcol + j * 32 + r32;
    const float bs = b2[col], ls = lsg[col];
#pragma unroll
    for (int r = 0; r < 16; ++r) {
      const int row = bm * 64 + wrow + 4 * h + (r & 3) + 8 * (r >> 2);
      out[(size_t)row * 1024 + col] =
          x[(size_t)row * 1024 + col] + (acc[j][r] + bs) * ls;
    }
  }
}

// ---------------- q/k per-head LN (bf16 out) + gelu (fp8 out), one launch
__global__ __launch_bounds__(256) void k_qkvgelu(const u16* __restrict__ f1,
                                                 const float* __restrict__ qg,
                                                 const float* __restrict__ qbb,
                                                 const float* __restrict__ kg,
                                                 const float* __restrict__ kbb,
                                                 u16* __restrict__ q,
                                                 u16* __restrict__ k,
                                                 u8* __restrict__ gel) {
  const int tid = threadIdx.x;
  if (blockIdx.x < 4096) {
    const int row = blockIdx.x;
    const int rem = tid >> 3;
    const int which = rem >> 4, h = rem & 15;
    const int e8 = (tid & 7) * 8;
    u16x8 xv = *(const u16x8*)(f1 + (size_t)row * 3840 + which * 1024 + h * 64 + e8);
    float xf[8];
    float s1 = 0.f, s2 = 0.f;
#pragma unroll
    for (int e = 0; e < 8; ++e) {
      xf[e] = bf2f(xv[e]);
      s1 += xf[e];
      s2 += xf[e] * xf[e];
    }
#pragma unroll
    for (int off = 1; off < 8; off <<= 1) {
      s1 += __shfl_xor(s1, off);
      s2 += __shfl_xor(s2, off);
    }
    const float mean = s1 * (1.f / 64.f);
    const float var = s2 * (1.f / 64.f) - mean * mean;
    const float rstd = rsqrtf(var + 1e-5f);
    const float* g = (which == 0) ? qg : kg;
    const float* bb = (which == 0) ? qbb : kbb;
    float4 g0 = ((const float4*)g)[e8 >> 2], g1 = ((const float4*)g)[(e8 >> 2) + 1];
    float4 b0 = ((const float4*)bb)[e8 >> 2], b1 = ((const float4*)bb)[(e8 >> 2) + 1];
    float gv[8] = {g0.x, g0.y, g0.z, g0.w, g1.x, g1.y, g1.z, g1.w};
    float bv[8] = {b0.x, b0.y, b0.z, b0.w, b1.x, b1.y, b1.z, b1.w};
    u16x8 o;
#pragma unroll
    for (int e = 0; e < 8; ++e) o[e] = f2bf((xf[e] - mean) * rstd * gv[e] + bv[e]);
    const int b = row >> 10, n = row & 1023;
    u16* dst = (which == 0) ? q : k;
    *(u16x8*)(dst + ((size_t)(b * 16 + h) * 1024 + n) * 64 + e8) = o;
  } else {
    const int id = (blockIdx.x - 4096) * 256 + tid;
    const int row = id / 96, c8 = id - row * 96;
    u16x8 xv = *(const u16x8*)(f1 + (size_t)row * 3840 + 3072 + c8 * 8);
    float rr[8];
#pragma unroll
    for (int e = 0; e < 8; ++e) {
      const int col = c8 * 8 + e;
      rr[e] = 0.f;
      if (col < 716) {
        float xx = bf2f(xv[e]);
        rr[e] = 0.5f * xx * (1.f + erff(xx * 0.70710678118654752f));
      }
    }
    int p0 = __builtin_amdgcn_cvt_pk_fp8_f32(rr[0], rr[1], 0, false);
    p0 = __builtin_amdgcn_cvt_pk_fp8_f32(rr[2], rr[3], p0, true);
    int p1 = __builtin_amdgcn_cvt_pk_fp8_f32(rr[4], rr[5], 0, false);
    p1 = __builtin_amdgcn_cvt_pk_fp8_f32(rr[6], rr[7], p1, true);
    uint2 pk;
    pk.x = (unsigned)p0;
    pk.y = (unsigned)p1;
    *(uint2*)(gel + (size_t)row * 768 + c8 * 8) = pk;
  }
}

// ---------------- flash attention v2: 128 threads (2 waves x 16 q-rows), grid 2048.
// XOR-swizzled unpadded LDS (64-u16 rows, 16B chunk pos = c ^ (row&7));
// K/V staged via async global_load_lds; P wave-private (lgkmcnt-ordered, no barrier).
__global__ __launch_bounds__(128) void k_flash(const u16* __restrict__ q,
                                               const u16* __restrict__ k,
                                               const u16* __restrict__ vt,
                                               u8* __restrict__ xo) {
  __shared__ __align__(16) u16 Kl[64 * 64];
  __shared__ __align__(16) u16 Vl[64 * 64];
  __shared__ __align__(16) u16 Pl[2 * 16 * 64];
  const int tid = threadIdx.x, wave = tid >> 6, lane = tid & 63;
  const int l15 = lane & 15, quad = lane >> 4;
  // XCD swizzle: all 32 q-tiles of one bh land on one XCD
  const int L = blockIdx.x;
  const int xcd = L & 7, i = L >> 3;
  const int bh = xcd * 8 + (i & 7), qt = i >> 3;  // qt 0..31
  const int qrow0 = qt * 32 + wave * 16;
  const u16* qb = q + ((size_t)bh * 1024 + qrow0) * 64;
  const u16* kb = k + (size_t)bh * 1024 * 64;
  const u16* vb = vt + (size_t)bh * 64 * 1024;
  u16* Pw = Pl + wave * 16 * 64;

  u16x8 qf[2];
#pragma unroll
  for (int kk = 0; kk < 2; ++kk)
    qf[kk] = *(const u16x8*)(qb + (size_t)l15 * 64 + (kk * 4 + quad) * 8);

  f32x4 O[4];
  float lacc[4] = {0.f, 0.f, 0.f, 0.f};
#pragma unroll
  for (int dt = 0; dt < 4; ++dt) O[dt] = f32x4{0.f, 0.f, 0.f, 0.f};

  const int pl7 = l15 & 7;
  for (int kv = 0; kv < 16; ++kv) {
    // stage K (64 keys x 64 d) and V^T (64 d x 64 keys), swizzled
#pragma unroll
    for (int p = 0; p < 4; ++p) {
      const int s = tid + 128 * p;
      const int r = s >> 3, pos = s & 7;
      const int c = pos ^ (r & 7);
      load_lds16(kb + (size_t)(kv * 64 + r) * 64 + c * 8, Kl + s * 8);
      load_lds16(vb + (size_t)r * 1024 + kv * 64 + c * 8, Vl + s * 8);
    }
    __syncthreads();  // drains vmcnt -> K/V visible
    f32x4 S[4];
#pragma unroll
    for (int j = 0; j < 4; ++j) S[j] = f32x4{0.f, 0.f, 0.f, 0.f};
#pragma unroll
    for (int j = 0; j < 4; ++j)
#pragma unroll
      for (int kk = 0; kk < 2; ++kk) {
        const int pos = (kk * 4 + quad) ^ pl7;
        u16x8 bfr = *(const u16x8*)(Kl + (16 * j + l15) * 64 + pos * 8);
        S[j] = mfma16(qf[kk], bfr, S[j]);
      }
    // no-max softmax (|s|<=8 after q/k LN); P wave-private
#pragma unroll
    for (int j = 0; j < 4; ++j)
#pragma unroll
      for (int r = 0; r < 4; ++r) {
        float pv = __expf(S[j][r] * 0.125f);
        lacc[r] += pv;
        const int prow = quad * 4 + r;
        const int pc = 2 * j + (l15 >> 3);
        Pw[prow * 64 + (pc ^ (prow & 7)) * 8 + pl7] = f2bf(pv);
      }
    // same-wave P RAW: force DS write completion before reads
    __builtin_amdgcn_s_waitcnt(0xC07F);  // lgkmcnt(0) only
#pragma unroll
    for (int c = 0; c < 2; ++c) {
      const int pos = (c * 4 + quad) ^ pl7;
      u16x8 pa = *(const u16x8*)(Pw + l15 * 64 + pos * 8);
#pragma unroll
      for (int dt = 0; dt < 4; ++dt) {
        u16x8 vf = *(const u16x8*)(Vl + (16 * dt + l15) * 64 + pos * 8);
        O[dt] = mfma16(pa, vf, O[dt]);
      }
    }
    __syncthreads();  // all waves done reading Kl/Vl before next staging
  }
#pragma unroll
  for (int r = 0; r < 4; ++r) {
#pragma unroll
    for (int off = 1; off < 16; off <<= 1) lacc[r] += __shfl_xor(lacc[r], off);
  }
  const int b = bh >> 4, h = bh & 15;
#pragma unroll
  for (int r = 0; r < 4; ++r) {
    const float inv = 1.f / lacc[r];
    u8* orow = xo + (size_t)(b * 1024 + qrow0 + quad * 4 + r) * 1024 + h * 64;
#pragma unroll
    for (int dt = 0; dt < 4; ++dt) orow[16 * dt + l15] = f2fp8(O[dt][r] * inv);
  }
}

extern "C" void kernel_launch(void* const* d_in, const int* in_sizes, int n_in,
                              void* d_out, int out_size, void* d_ws, size_t ws_size,
                              hipStream_t stream) {
  (void)in_sizes; (void)n_in; (void)out_size; (void)ws_size;
  const float* x      = (const float*)d_in[0];
  const float* norm_g = (const float*)d_in[1];
  const float* norm_b = (const float*)d_in[2];
  const float* W1     = (const float*)d_in[3];
  const float* b1     = (const float*)d_in[4];
  const float* qn_g   = (const float*)d_in[5];
  const float* qn_b   = (const float*)d_in[6];
  const float* kn_g   = (const float*)d_in[7];
  const float* kn_b   = (const float*)d_in[8];
  const float* projW  = (const float*)d_in[9];
  const float* projb  = (const float*)d_in[10];
  const float* mlpW   = (const float*)d_in[11];
  const float* W2     = (const float*)d_in[12];
  const float* b2     = (const float*)d_in[13];
  const float* ls_g   = (const float*)d_in[14];

  char* ws = (char*)d_ws;
  u8*  W1t8 = (u8*)(ws + 0);           // [3840][1024]  3,932,160
  u8*  pWt8 = (u8*)(ws + 3932160);     // [1024][1024]  1,048,576
  u8*  mWt8 = (u8*)(ws + 4980736);     // [1024][768]     786,432
  u8*  W2t8 = (u8*)(ws + 5767168);     // [1024][2048]  2,097,152
  u8*  nx8  = (u8*)(ws + 7864320);     // [4096][1024]  4,194,304 (then xo8)
  u16* f1   = (u16*)(ws + 12058624);   // [4096][3840] 31,457,280 bf16 (then comb fp8)
  u16* qbuf = (u16*)(ws + 43515904);   // [64][1024][64] 8,388,608
  u16* kbuf = (u16*)(ws + 51904512);   // [64][1024][64] 8,388,608
  u16* vtb  = (u16*)(ws + 60293120);   // [64][64][1024] 8,388,608
  u8*  gel8 = (u8*)(ws + 68681728);    // [4096][768]   3,145,728

  k_trcvt_all<<<7680, 256, 0, stream>>>(W1, projW, mlpW, W2, W1t8, pWt8, mWt8, W2t8);
  k_lnx<<<4096, 256, 0, stream>>>(x, norm_g, norm_b, nx8);
  k_gemm1<<<dim3(30, 32), 256, 0, stream>>>(nx8, W1t8, f1, b1);
  k_qkvgelu<<<5632, 256, 0, stream>>>(f1, qn_g, qn_b, kn_g, kn_b, qbuf, kbuf, gel8);
  k_trvt<<<dim3(2, 32, 64), 256, 0, stream>>>(f1, vtb);
  k_flash<<<2048, 128, 0, stream>>>(qbuf, kbuf, vtb, nx8);
  k_gemm_pm<<<dim3(16, 64), 256, 0, stream>>>(nx8, pWt8, gel8, mWt8, (u8*)f1, projb);
  k_gemm_fin<<<dim3(8, 64), 256, 0, stream>>>((u8*)f1, W2t8, (float*)d_out, b2, x,
                                              ls_g);
}